// Round 7
// baseline (617.023 us; speedup 1.0000x reference)
//
#include <hip/hip_runtime.h>
#include <cstdint>
#include <cstddef>

typedef __attribute__((ext_vector_type(4))) float f32x4;
typedef __attribute__((ext_vector_type(8))) _Float16 half8v;
typedef __attribute__((ext_vector_type(2))) _Float16 half2v;

static inline int cdiv(int a, int b){ return (a + b - 1) / b; }

#define BSH 6              // bucket shift: 64 nodes per bucket
#define BCAP 2048          // max edges per bucket (expected ~1024, sd ~32)

// ---------------- fused: weight-convert (blocks 0..223) || degree count (rest) ----------------

__global__ __launch_bounds__(256) void wcvt_count_kernel(const float* __restrict__ W1, _Float16* __restrict__ W1t,
                                                         const float* __restrict__ W2, _Float16* __restrict__ W2t,
                                                         const float* __restrict__ W3, _Float16* __restrict__ W3t,
                                                         const int* __restrict__ dst, int* __restrict__ counts, int E){
  int b = blockIdx.x;
  if (b < 224){
    int i = b * 256 + threadIdx.x;
    if (b < 128){
      int k = i / 128, n = i & 127;
      W1t[(size_t)n * 256 + k] = (_Float16)W1[i];
    } else if (b < 192){
      int j = i - 128 * 256;
      int k = j / 128, n = j & 127;
      W2t[(size_t)n * 128 + k] = (_Float16)W2[j];
    } else {
      int j = i - 192 * 256;
      int k = j / 64, n = j & 63;
      W3t[(size_t)n * 128 + k] = (_Float16)W3[j];
    }
    return;
  }
  int cb = b - 224;
  int base = cb * 1024 + threadIdx.x;
  #pragma unroll
  for (int j = 0; j < 4; j++){
    int i = base + j * 256;
    if (i < E) atomicAdd(&counts[__builtin_nontemporal_load(dst + i)], 1);
  }
}

// ---------------- block partial sums (+ fused dinv) ----------------

__global__ __launch_bounds__(256) void partial_dinv_kernel(const int* __restrict__ counts, int* __restrict__ bsum,
                                                           float* __restrict__ dinv, int n){
  __shared__ int sdata[256];
  int b = blockIdx.x, t = threadIdx.x;
  int base = b * 1024 + t * 4;
  int s = 0;
  #pragma unroll
  for (int i = 0; i < 4; i++){
    if (base + i < n){
      int c = counts[base + i];
      s += c;
      dinv[base + i] = rsqrtf((float)c + 1.0f);
    }
  }
  sdata[t] = s; __syncthreads();
  for (int off = 128; off > 0; off >>= 1){
    if (t < off) sdata[t] += sdata[t + off];
    __syncthreads();
  }
  if (t == 0) bsum[b] = sdata[0];
}

__global__ void scan_partials_kernel(const int* __restrict__ bsum, int* __restrict__ bsum_ex,
                                     int* __restrict__ row_off, int nblocks, int n){
  int run = 0;
  for (int i = 0; i < nblocks; i++){ bsum_ex[i] = run; run += bsum[i]; }
  row_off[n] = run;
}

// scan chunk; also emits bucket cursors bcur[b] = row_off[b<<BSH]

__global__ __launch_bounds__(256) void scan_chunk_kernel(const int* __restrict__ counts, const int* __restrict__ bsum_ex,
                                                         int* __restrict__ row_off, int* __restrict__ bcur, int n){
  __shared__ int sdata[256];
  int b = blockIdx.x, t = threadIdx.x;
  int base = b * 1024 + t * 4;
  int c0 = (base + 0 < n) ? counts[base + 0] : 0;
  int c1 = (base + 1 < n) ? counts[base + 1] : 0;
  int c2 = (base + 2 < n) ? counts[base + 2] : 0;
  int c3 = (base + 3 < n) ? counts[base + 3] : 0;
  int tsum = c0 + c1 + c2 + c3;
  sdata[t] = tsum; __syncthreads();
  for (int off = 1; off < 256; off <<= 1){
    int v = (t >= off) ? sdata[t - off] : 0;
    __syncthreads();
    sdata[t] += v;
    __syncthreads();
  }
  int run = bsum_ex[b] + sdata[t] - tsum;
  if (base < n && (base & ((1 << BSH) - 1)) == 0) bcur[base >> BSH] = run;
  if (base + 0 < n){ row_off[base + 0] = run; run += c0; }
  if (base + 1 < n){ row_off[base + 1] = run; run += c1; }
  if (base + 2 < n){ row_off[base + 2] = run; run += c2; }
  if (base + 3 < n){ row_off[base + 3] = run; run += c3; }
}

// ---------------- CSR pass 2: bucket scatter ----------------
// p = bcur[dst>>BSH]++ grows sequentially per bucket -> 64B lines complete within ~16
// temporally-adjacent reservations -> L2 write-coalescing works (vs random per-node scatter).
// payload packed to 4B: src<<BSH | (dst & 63).

__global__ __launch_bounds__(256) void bucket_scatter_kernel(const int* __restrict__ src, const int* __restrict__ dst,
                                                             int* __restrict__ bcur, unsigned* __restrict__ tmp, int E){
  int stride = gridDim.x * 256;
  for (int i = blockIdx.x * 256 + threadIdx.x; i < E; i += stride){
    int d = __builtin_nontemporal_load(dst + i);
    int s = __builtin_nontemporal_load(src + i);
    int p = atomicAdd(&bcur[d >> BSH], 1);
    tmp[p] = ((unsigned)s << BSH) | (unsigned)(d & ((1 << BSH) - 1));
  }
}

// ---------------- CSR pass 3: per-bucket LDS counting sort, coalesced csr write ----------------

__global__ __launch_bounds__(256) void bucket_sort_kernel(const unsigned* __restrict__ tmp, const int* __restrict__ row_off,
                                                          int* __restrict__ csr_src, int N){
  __shared__ int lcur[1 << BSH];
  __shared__ int lds_csr[BCAP];
  int g = blockIdx.x;
  int base = g << BSH;
  int nloc = N - base; if (nloc > (1 << BSH)) nloc = (1 << BSH);
  int t = threadIdx.x;
  int region_start = row_off[base];
  int region_end   = row_off[base + nloc];
  int bsz = region_end - region_start;
  if (t < (1 << BSH)) lcur[t] = (t < nloc) ? (row_off[base + t] - region_start) : 0;
  __syncthreads();
  if (bsz <= BCAP){
    for (int i = t; i < bsz; i += 256){
      unsigned v = tmp[region_start + i];
      int slot = atomicAdd(&lcur[v & ((1 << BSH) - 1)], 1);
      lds_csr[slot] = (int)(v >> BSH);
    }
    __syncthreads();
    for (int i = t; i < bsz; i += 256)
      csr_src[region_start + i] = lds_csr[i];
  } else {
    for (int i = t; i < bsz; i += 256){
      unsigned v = tmp[region_start + i];
      int slot = atomicAdd(&lcur[v & ((1 << BSH) - 1)], 1);
      csr_src[region_start + slot] = (int)(v >> BSH);
    }
  }
}

// ---------------- MFMA GEMM: C16[M x BN] = fp16(A @ Bt^T), Bt is [BN x K] fp16 ----------------
// BM=128, BK=32, 4 waves. v_mfma_f32_16x16x32_f16:
//   A: lane l row (l&15), k = 8*(l>>4)+{0..7}; B: lane l col (l&15), same k
//   D: lane l reg r -> row = 4*(l>>4)+r, col = (l&15)

template<int BN, bool A32IN>
__global__ __launch_bounds__(256) void mgemm_kernel(const void* __restrict__ Ain, const _Float16* __restrict__ Bt,
                                                    _Float16* __restrict__ C16, int M, int K){
  constexpr int BM = 128, LD = 40;   // stride 40 halves: 16B-aligned rows, <=2-way bank aliasing
  constexpr int MF = (BN == 128) ? 4 : 2;
  __shared__ _Float16 As[BM * LD];
  __shared__ _Float16 Bs[BN * LD];
  const float*    A32 = (const float*)Ain;
  const _Float16* A16 = (const _Float16*)Ain;
  int t = threadIdx.x;
  int w = t >> 6, l = t & 63;
  int m0 = blockIdx.x * BM;
  int wm = (BN == 128) ? (w >> 1) * 64 : w * 32;
  int wn = (BN == 128) ? (w & 1) * 64 : 0;
  int lr = l & 15;
  int kg = (l >> 4) * 8;

  f32x4 acc[MF][4];
  #pragma unroll
  for (int i = 0; i < MF; i++)
    #pragma unroll
    for (int j = 0; j < 4; j++){
      f32x4 z = {0.f, 0.f, 0.f, 0.f};
      acc[i][j] = z;
    }

  for (int k0 = 0; k0 < K; k0 += 32){
    __syncthreads();
    #pragma unroll
    for (int j = 0; j < (BM * 4) / 256; j++){
      int i = t + j * 256;
      int row = i >> 2, c = i & 3;
      int gr = m0 + row;
      half8v hv = {(_Float16)0, (_Float16)0, (_Float16)0, (_Float16)0,
                   (_Float16)0, (_Float16)0, (_Float16)0, (_Float16)0};
      if (gr < M){
        if (A32IN){
          const float* ap = A32 + (size_t)gr * K + k0 + c * 8;
          float4 f0 = *reinterpret_cast<const float4*>(ap);
          float4 f1 = *reinterpret_cast<const float4*>(ap + 4);
          hv[0] = (_Float16)f0.x; hv[1] = (_Float16)f0.y; hv[2] = (_Float16)f0.z; hv[3] = (_Float16)f0.w;
          hv[4] = (_Float16)f1.x; hv[5] = (_Float16)f1.y; hv[6] = (_Float16)f1.z; hv[7] = (_Float16)f1.w;
        } else {
          hv = *reinterpret_cast<const half8v*>(A16 + (size_t)gr * K + k0 + c * 8);
        }
      }
      *reinterpret_cast<half8v*>(&As[row * LD + c * 8]) = hv;
    }
    #pragma unroll
    for (int j = 0; j < (BN * 4) / 256; j++){
      int i = t + j * 256;
      int row = i >> 2, c = i & 3;
      *reinterpret_cast<half8v*>(&Bs[row * LD + c * 8]) =
        *reinterpret_cast<const half8v*>(Bt + (size_t)row * K + k0 + c * 8);
    }
    __syncthreads();
    half8v af[MF];
    #pragma unroll
    for (int mf = 0; mf < MF; mf++)
      af[mf] = *reinterpret_cast<const half8v*>(&As[(wm + mf * 16 + lr) * LD + kg]);
    #pragma unroll
    for (int nf = 0; nf < 4; nf++){
      half8v bf = *reinterpret_cast<const half8v*>(&Bs[(wn + nf * 16 + lr) * LD + kg]);
      #pragma unroll
      for (int mf = 0; mf < MF; mf++)
        acc[mf][nf] = __builtin_amdgcn_mfma_f32_16x16x32_f16(af[mf], bf, acc[mf][nf], 0, 0, 0);
    }
  }
  #pragma unroll
  for (int mf = 0; mf < MF; mf++){
    #pragma unroll
    for (int r = 0; r < 4; r++){
      int row = m0 + wm + mf * 16 + (l >> 4) * 4 + r;
      if (row < M){
        #pragma unroll
        for (int nf = 0; nf < 4; nf++)
          C16[(size_t)row * BN + wn + nf * 16 + lr] = (_Float16)acc[mf][nf][r];
      }
    }
  }
}

// ---------------- aggregation (fp16 gather): out = relu(di*(sum dinv_s h_s) + di^2 h_i + b) ----------------

__global__ __launch_bounds__(256) void agg128h_kernel(const _Float16* __restrict__ h16, const int* __restrict__ row_off,
                                                      const int* __restrict__ csr_src, const float* __restrict__ dinv,
                                                      const float* __restrict__ bias, _Float16* __restrict__ out16, int n){
  int node = blockIdx.x * 4 + (threadIdx.x >> 6);
  if (node >= n) return;
  int lane = threadIdx.x & 63;
  int e = row_off[node], eend = row_off[node + 1];
  float di = dinv[node];
  float ax = 0.f, ay = 0.f;
  for (; e + 8 <= eend; e += 8){
    int s[8]; float w[8]; half2v v[8];
    #pragma unroll
    for (int i = 0; i < 8; i++) s[i] = csr_src[e + i];
    #pragma unroll
    for (int i = 0; i < 8; i++) w[i] = dinv[s[i]];
    #pragma unroll
    for (int i = 0; i < 8; i++)
      v[i] = *reinterpret_cast<const half2v*>(h16 + (size_t)s[i] * 128 + lane * 2);
    #pragma unroll
    for (int i = 0; i < 8; i++){
      ax = fmaf(w[i], (float)v[i][0], ax);
      ay = fmaf(w[i], (float)v[i][1], ay);
    }
  }
  for (; e < eend; ++e){
    int s = csr_src[e];
    float w = dinv[s];
    half2v v = *reinterpret_cast<const half2v*>(h16 + (size_t)s * 128 + lane * 2);
    ax = fmaf(w, (float)v[0], ax);
    ay = fmaf(w, (float)v[1], ay);
  }
  half2v hv = *reinterpret_cast<const half2v*>(h16 + (size_t)node * 128 + lane * 2);
  float2 bv = *reinterpret_cast<const float2*>(bias + lane * 2);
  float ox = fmaxf(fmaf(di, ax, di * di * (float)hv[0]) + bv.x, 0.f);
  float oy = fmaxf(fmaf(di, ay, di * di * (float)hv[1]) + bv.y, 0.f);
  half2v o; o[0] = (_Float16)ox; o[1] = (_Float16)oy;
  *reinterpret_cast<half2v*>(out16 + (size_t)node * 128 + lane * 2) = o;
}

// layer-3 agg (64-dim) with fused classifier: out[node] = dot(relu(agg), Wc) + bc

__global__ __launch_bounds__(256) void agg64h_cls_kernel(const _Float16* __restrict__ h16, const int* __restrict__ row_off,
                                                         const int* __restrict__ csr_src, const float* __restrict__ dinv,
                                                         const float* __restrict__ bias, const float* __restrict__ Wc,
                                                         const float* __restrict__ bc, float* __restrict__ out, int n){
  int node = blockIdx.x * 4 + (threadIdx.x >> 6);
  if (node >= n) return;
  int lane = threadIdx.x & 63;
  int e = row_off[node], eend = row_off[node + 1];
  float di = dinv[node];
  float ax = 0.f;
  for (; e + 8 <= eend; e += 8){
    int s[8]; float w[8]; _Float16 v[8];
    #pragma unroll
    for (int i = 0; i < 8; i++) s[i] = csr_src[e + i];
    #pragma unroll
    for (int i = 0; i < 8; i++) w[i] = dinv[s[i]];
    #pragma unroll
    for (int i = 0; i < 8; i++) v[i] = h16[(size_t)s[i] * 64 + lane];
    #pragma unroll
    for (int i = 0; i < 8; i++) ax = fmaf(w[i], (float)v[i], ax);
  }
  for (; e < eend; ++e){
    int s = csr_src[e];
    ax = fmaf(dinv[s], (float)h16[(size_t)s * 64 + lane], ax);
  }
  float hv = (float)h16[(size_t)node * 64 + lane];
  float o = fmaxf(fmaf(di, ax, di * di * hv) + bias[lane], 0.f);
  float v = o * Wc[lane];
  #pragma unroll
  for (int off = 32; off > 0; off >>= 1) v += __shfl_down(v, off);
  if (lane == 0) out[node] = v + bc[0];
}

// ---------------- launch ----------------

extern "C" void kernel_launch(void* const* d_in, const int* in_sizes, int n_in,
                              void* d_out, int out_size, void* d_ws, size_t ws_size,
                              hipStream_t stream){
  const float* x  = (const float*)d_in[0];
  const int*   ei = (const int*)d_in[1];
  const float* W1 = (const float*)d_in[2];
  const float* b1 = (const float*)d_in[3];
  const float* W2 = (const float*)d_in[4];
  const float* b2 = (const float*)d_in[5];
  const float* W3 = (const float*)d_in[6];
  const float* b3 = (const float*)d_in[7];
  const float* Wc = (const float*)d_in[8];
  const float* bc = (const float*)d_in[9];
  float* out = (float*)d_out;

  int N = in_sizes[0] / 256;
  int E = in_sizes[1] / 2;
  const int* src = ei;
  const int* dst = ei + E;
  int NBK = (N + (1 << BSH) - 1) >> BSH;

  char* ws = (char*)d_ws;
  size_t off = 0;
  auto alloc = [&](size_t bytes) -> char* {
    char* p = ws + off;
    off += (bytes + 511) & ~(size_t)511;
    return p;
  };
  int*      counts  = (int*)     alloc((size_t)N * 4);
  float*    dinv    = (float*)   alloc((size_t)N * 4);
  int*      row_off = (int*)     alloc(((size_t)N + 1) * 4);
  int*      bsum    = (int*)     alloc(1024);
  int*      bsum_ex = (int*)     alloc(1024);
  int*      bcur    = (int*)     alloc((size_t)NBK * 4);
  unsigned* tmp     = (unsigned*)alloc((size_t)E * 4);
  int*      csr_src = (int*)     alloc((size_t)E * 4);
  _Float16* bufH    = (_Float16*)alloc((size_t)N * 128 * 2);  // gemm outputs
  _Float16* bufG    = (_Float16*)alloc((size_t)N * 128 * 2);  // agg outputs (fp16)
  _Float16* W1t     = (_Float16*)alloc((size_t)256 * 128 * 2);
  _Float16* W2t     = (_Float16*)alloc((size_t)128 * 128 * 2);
  _Float16* W3t     = (_Float16*)alloc((size_t)128 * 64 * 2);

  int NB = (N + 1023) / 1024;

  // K1: wcvt (224 blocks) || degree count
  hipMemsetAsync(counts, 0, (size_t)N * 4, stream);
  wcvt_count_kernel<<<224 + cdiv(E, 1024), 256, 0, stream>>>(W1, W1t, W2, W2t, W3, W3t, dst, counts, E);
  // K2: scan chain (+ dinv, + bcur init fused)
  partial_dinv_kernel<<<NB, 256, 0, stream>>>(counts, bsum, dinv, N);
  scan_partials_kernel<<<1, 1, 0, stream>>>(bsum, bsum_ex, row_off, NB, N);
  scan_chunk_kernel<<<NB, 256, 0, stream>>>(counts, bsum_ex, row_off, bcur, N);
  // K3: CSR via bucket scatter + per-bucket LDS sort
  bucket_scatter_kernel<<<1024, 256, 0, stream>>>(src, dst, bcur, tmp, E);
  bucket_sort_kernel<<<NBK, 256, 0, stream>>>(tmp, row_off, csr_src, N);
  // layer 1: x[N,256] @ W1 -> bufH (fp16); agg -> bufG (fp16)
  mgemm_kernel<128, true ><<<cdiv(N, 128), 256, 0, stream>>>(x, W1t, bufH, N, 256);
  agg128h_kernel<<<cdiv(N, 4), 256, 0, stream>>>(bufH, row_off, csr_src, dinv, b1, bufG, N);
  // layer 2
  mgemm_kernel<128, false><<<cdiv(N, 128), 256, 0, stream>>>(bufG, W2t, bufH, N, 128);
  agg128h_kernel<<<cdiv(N, 4), 256, 0, stream>>>(bufH, row_off, csr_src, dinv, b2, bufG, N);
  // layer 3 (128 -> 64) + fused classifier
  mgemm_kernel<64, false><<<cdiv(N, 128), 256, 0, stream>>>(bufG, W3t, bufH, N, 128);
  agg64h_cls_kernel<<<cdiv(N, 4), 256, 0, stream>>>(bufH, row_off, csr_src, dinv, b3, Wc, bc, out, N);
}

// Round 8
// 412.784 us; speedup vs baseline: 1.4948x; 1.4948x over previous
//
#include <hip/hip_runtime.h>
#include <cstdint>
#include <cstddef>

typedef __attribute__((ext_vector_type(4))) float f32x4;
typedef __attribute__((ext_vector_type(8))) _Float16 half8v;
typedef __attribute__((ext_vector_type(2))) _Float16 half2v;

static inline int cdiv(int a, int b){ return (a + b - 1) / b; }

#define BSH 9              // bucket shift: 512 nodes per bucket
#define CH 8192            // edges staged per scatter block

// ---------------- fused: weight-convert (blocks 0..223) || degree count (rest) ----------------

__global__ __launch_bounds__(256) void wcvt_count_kernel(const float* __restrict__ W1, _Float16* __restrict__ W1t,
                                                         const float* __restrict__ W2, _Float16* __restrict__ W2t,
                                                         const float* __restrict__ W3, _Float16* __restrict__ W3t,
                                                         const int* __restrict__ dst, int* __restrict__ counts, int E){
  int b = blockIdx.x;
  if (b < 224){
    int i = b * 256 + threadIdx.x;
    if (b < 128){
      int k = i / 128, n = i & 127;
      W1t[(size_t)n * 256 + k] = (_Float16)W1[i];
    } else if (b < 192){
      int j = i - 128 * 256;
      int k = j / 128, n = j & 127;
      W2t[(size_t)n * 128 + k] = (_Float16)W2[j];
    } else {
      int j = i - 192 * 256;
      int k = j / 64, n = j & 63;
      W3t[(size_t)n * 128 + k] = (_Float16)W3[j];
    }
    return;
  }
  int cb = b - 224;
  int base = cb * 1024 + threadIdx.x;
  #pragma unroll
  for (int j = 0; j < 4; j++){
    int i = base + j * 256;
    if (i < E) atomicAdd(&counts[__builtin_nontemporal_load(dst + i)], 1);
  }
}

// ---------------- block partial sums (+ fused dinv) ----------------

__global__ __launch_bounds__(256) void partial_dinv_kernel(const int* __restrict__ counts, int* __restrict__ bsum,
                                                           float* __restrict__ dinv, int n){
  __shared__ int sdata[256];
  int b = blockIdx.x, t = threadIdx.x;
  int base = b * 1024 + t * 4;
  int s = 0;
  #pragma unroll
  for (int i = 0; i < 4; i++){
    if (base + i < n){
      int c = counts[base + i];
      s += c;
      dinv[base + i] = rsqrtf((float)c + 1.0f);
    }
  }
  sdata[t] = s; __syncthreads();
  for (int off = 128; off > 0; off >>= 1){
    if (t < off) sdata[t] += sdata[t + off];
    __syncthreads();
  }
  if (t == 0) bsum[b] = sdata[0];
}

__global__ void scan_partials_kernel(const int* __restrict__ bsum, int* __restrict__ bsum_ex,
                                     int* __restrict__ row_off, int nblocks, int n){
  int run = 0;
  for (int i = 0; i < nblocks; i++){ bsum_ex[i] = run; run += bsum[i]; }
  row_off[n] = run;
}

// scan chunk; also emits bucket cursors bcur[b] = row_off[b<<BSH]

__global__ __launch_bounds__(256) void scan_chunk_kernel(const int* __restrict__ counts, const int* __restrict__ bsum_ex,
                                                         int* __restrict__ row_off, int* __restrict__ bcur, int n){
  __shared__ int sdata[256];
  int b = blockIdx.x, t = threadIdx.x;
  int base = b * 1024 + t * 4;
  int c0 = (base + 0 < n) ? counts[base + 0] : 0;
  int c1 = (base + 1 < n) ? counts[base + 1] : 0;
  int c2 = (base + 2 < n) ? counts[base + 2] : 0;
  int c3 = (base + 3 < n) ? counts[base + 3] : 0;
  int tsum = c0 + c1 + c2 + c3;
  sdata[t] = tsum; __syncthreads();
  for (int off = 1; off < 256; off <<= 1){
    int v = (t >= off) ? sdata[t - off] : 0;
    __syncthreads();
    sdata[t] += v;
    __syncthreads();
  }
  int run = bsum_ex[b] + sdata[t] - tsum;
  if (base < n && (base & ((1 << BSH) - 1)) == 0) bcur[base >> BSH] = run;
  if (base + 0 < n){ row_off[base + 0] = run; run += c0; }
  if (base + 1 < n){ row_off[base + 1] = run; run += c1; }
  if (base + 2 < n){ row_off[base + 2] = run; run += c2; }
  if (base + 3 < n){ row_off[base + 3] = run; run += c3; }
}

// ---------------- CSR pass 2: block-histogram bucket scatter ----------------
// Per block: stage CH edges in LDS, LDS histogram over buckets, ONE global atomicAdd per
// (block,bucket) to reserve a contiguous run, then scatter LDS->tmp in ~168B runs.
// Kills the per-edge same-address atomic serialization that cost round 7 239us.

__global__ __launch_bounds__(256) void bucket_scatter_kernel(const int* __restrict__ src, const int* __restrict__ dst,
                                                             int* __restrict__ bcur, unsigned* __restrict__ tmp,
                                                             int E, int NBK){
  __shared__ int hist[1024];
  __shared__ int hbase[1024];
  __shared__ unsigned pk[CH];
  __shared__ unsigned short bkt[CH];
  int t = threadIdx.x;
  int e0 = blockIdx.x * CH;
  int e1 = e0 + CH; if (e1 > E) e1 = E;
  int nloc = e1 - e0;
  for (int i = t; i < NBK; i += 256) hist[i] = 0;
  __syncthreads();
  for (int i = t; i < nloc; i += 256){
    int d = __builtin_nontemporal_load(dst + e0 + i);
    int s = __builtin_nontemporal_load(src + e0 + i);
    int b = d >> BSH;
    pk[i]  = ((unsigned)s << BSH) | (unsigned)(d & ((1 << BSH) - 1));
    bkt[i] = (unsigned short)b;
    atomicAdd(&hist[b], 1);
  }
  __syncthreads();
  for (int i = t; i < NBK; i += 256){
    int h = hist[i];
    hbase[i] = h ? atomicAdd(&bcur[i], h) : 0;
    hist[i] = 0;                         // reuse as intra-block cursor
  }
  __syncthreads();
  for (int i = t; i < nloc; i += 256){
    int b = bkt[i];
    int pos = atomicAdd(&hist[b], 1);
    tmp[hbase[b] + pos] = pk[i];
  }
}

// ---------------- CSR pass 3: per-bucket LDS-cursor sort, writes within a 32KB window ----------------

__global__ __launch_bounds__(256) void bucket_sort_kernel(const unsigned* __restrict__ tmp, const int* __restrict__ row_off,
                                                          int* __restrict__ csr_src, int N){
  __shared__ int lcur[1 << BSH];
  int g = blockIdx.x;
  int base = g << BSH;
  int nloc = N - base; if (nloc > (1 << BSH)) nloc = (1 << BSH);
  int t = threadIdx.x;
  for (int i = t; i < nloc; i += 256) lcur[i] = row_off[base + i];
  __syncthreads();
  int rs = row_off[base], re = row_off[base + nloc];
  for (int i = rs + t; i < re; i += 256){
    unsigned v = tmp[i];
    int slot = atomicAdd(&lcur[v & ((1 << BSH) - 1)], 1);
    csr_src[slot] = (int)(v >> BSH);
  }
}

// ---------------- MFMA GEMM: C16[M x BN] = fp16(A @ Bt^T), Bt is [BN x K] fp16 ----------------
// BM=128, BK=32, 4 waves. v_mfma_f32_16x16x32_f16:
//   A: lane l row (l&15), k = 8*(l>>4)+{0..7}; B: lane l col (l&15), same k
//   D: lane l reg r -> row = 4*(l>>4)+r, col = (l&15)

template<int BN, bool A32IN>
__global__ __launch_bounds__(256) void mgemm_kernel(const void* __restrict__ Ain, const _Float16* __restrict__ Bt,
                                                    _Float16* __restrict__ C16, int M, int K){
  constexpr int BM = 128, LD = 40;   // stride 40 halves: 16B-aligned rows, <=2-way bank aliasing
  constexpr int MF = (BN == 128) ? 4 : 2;
  __shared__ _Float16 As[BM * LD];
  __shared__ _Float16 Bs[BN * LD];
  const float*    A32 = (const float*)Ain;
  const _Float16* A16 = (const _Float16*)Ain;
  int t = threadIdx.x;
  int w = t >> 6, l = t & 63;
  int m0 = blockIdx.x * BM;
  int wm = (BN == 128) ? (w >> 1) * 64 : w * 32;
  int wn = (BN == 128) ? (w & 1) * 64 : 0;
  int lr = l & 15;
  int kg = (l >> 4) * 8;

  f32x4 acc[MF][4];
  #pragma unroll
  for (int i = 0; i < MF; i++)
    #pragma unroll
    for (int j = 0; j < 4; j++){
      f32x4 z = {0.f, 0.f, 0.f, 0.f};
      acc[i][j] = z;
    }

  for (int k0 = 0; k0 < K; k0 += 32){
    __syncthreads();
    #pragma unroll
    for (int j = 0; j < (BM * 4) / 256; j++){
      int i = t + j * 256;
      int row = i >> 2, c = i & 3;
      int gr = m0 + row;
      half8v hv = {(_Float16)0, (_Float16)0, (_Float16)0, (_Float16)0,
                   (_Float16)0, (_Float16)0, (_Float16)0, (_Float16)0};
      if (gr < M){
        if (A32IN){
          const float* ap = A32 + (size_t)gr * K + k0 + c * 8;
          float4 f0 = *reinterpret_cast<const float4*>(ap);
          float4 f1 = *reinterpret_cast<const float4*>(ap + 4);
          hv[0] = (_Float16)f0.x; hv[1] = (_Float16)f0.y; hv[2] = (_Float16)f0.z; hv[3] = (_Float16)f0.w;
          hv[4] = (_Float16)f1.x; hv[5] = (_Float16)f1.y; hv[6] = (_Float16)f1.z; hv[7] = (_Float16)f1.w;
        } else {
          hv = *reinterpret_cast<const half8v*>(A16 + (size_t)gr * K + k0 + c * 8);
        }
      }
      *reinterpret_cast<half8v*>(&As[row * LD + c * 8]) = hv;
    }
    #pragma unroll
    for (int j = 0; j < (BN * 4) / 256; j++){
      int i = t + j * 256;
      int row = i >> 2, c = i & 3;
      *reinterpret_cast<half8v*>(&Bs[row * LD + c * 8]) =
        *reinterpret_cast<const half8v*>(Bt + (size_t)row * K + k0 + c * 8);
    }
    __syncthreads();
    half8v af[MF];
    #pragma unroll
    for (int mf = 0; mf < MF; mf++)
      af[mf] = *reinterpret_cast<const half8v*>(&As[(wm + mf * 16 + lr) * LD + kg]);
    #pragma unroll
    for (int nf = 0; nf < 4; nf++){
      half8v bf = *reinterpret_cast<const half8v*>(&Bs[(wn + nf * 16 + lr) * LD + kg]);
      #pragma unroll
      for (int mf = 0; mf < MF; mf++)
        acc[mf][nf] = __builtin_amdgcn_mfma_f32_16x16x32_f16(af[mf], bf, acc[mf][nf], 0, 0, 0);
    }
  }
  #pragma unroll
  for (int mf = 0; mf < MF; mf++){
    #pragma unroll
    for (int r = 0; r < 4; r++){
      int row = m0 + wm + mf * 16 + (l >> 4) * 4 + r;
      if (row < M){
        #pragma unroll
        for (int nf = 0; nf < 4; nf++)
          C16[(size_t)row * BN + wn + nf * 16 + lr] = (_Float16)acc[mf][nf][r];
      }
    }
  }
}

// ---------------- aggregation (fp16 gather): out = relu(di*(sum dinv_s h_s) + di^2 h_i + b) ----------------

__global__ __launch_bounds__(256) void agg128h_kernel(const _Float16* __restrict__ h16, const int* __restrict__ row_off,
                                                      const int* __restrict__ csr_src, const float* __restrict__ dinv,
                                                      const float* __restrict__ bias, _Float16* __restrict__ out16, int n){
  int node = blockIdx.x * 4 + (threadIdx.x >> 6);
  if (node >= n) return;
  int lane = threadIdx.x & 63;
  int e = row_off[node], eend = row_off[node + 1];
  float di = dinv[node];
  float ax = 0.f, ay = 0.f;
  for (; e + 8 <= eend; e += 8){
    int s[8]; float w[8]; half2v v[8];
    #pragma unroll
    for (int i = 0; i < 8; i++) s[i] = csr_src[e + i];
    #pragma unroll
    for (int i = 0; i < 8; i++) w[i] = dinv[s[i]];
    #pragma unroll
    for (int i = 0; i < 8; i++)
      v[i] = *reinterpret_cast<const half2v*>(h16 + (size_t)s[i] * 128 + lane * 2);
    #pragma unroll
    for (int i = 0; i < 8; i++){
      ax = fmaf(w[i], (float)v[i][0], ax);
      ay = fmaf(w[i], (float)v[i][1], ay);
    }
  }
  for (; e < eend; ++e){
    int s = csr_src[e];
    float w = dinv[s];
    half2v v = *reinterpret_cast<const half2v*>(h16 + (size_t)s * 128 + lane * 2);
    ax = fmaf(w, (float)v[0], ax);
    ay = fmaf(w, (float)v[1], ay);
  }
  half2v hv = *reinterpret_cast<const half2v*>(h16 + (size_t)node * 128 + lane * 2);
  float2 bv = *reinterpret_cast<const float2*>(bias + lane * 2);
  float ox = fmaxf(fmaf(di, ax, di * di * (float)hv[0]) + bv.x, 0.f);
  float oy = fmaxf(fmaf(di, ay, di * di * (float)hv[1]) + bv.y, 0.f);
  half2v o; o[0] = (_Float16)ox; o[1] = (_Float16)oy;
  *reinterpret_cast<half2v*>(out16 + (size_t)node * 128 + lane * 2) = o;
}

// layer-3 agg (64-dim) with fused classifier: out[node] = dot(relu(agg), Wc) + bc

__global__ __launch_bounds__(256) void agg64h_cls_kernel(const _Float16* __restrict__ h16, const int* __restrict__ row_off,
                                                         const int* __restrict__ csr_src, const float* __restrict__ dinv,
                                                         const float* __restrict__ bias, const float* __restrict__ Wc,
                                                         const float* __restrict__ bc, float* __restrict__ out, int n){
  int node = blockIdx.x * 4 + (threadIdx.x >> 6);
  if (node >= n) return;
  int lane = threadIdx.x & 63;
  int e = row_off[node], eend = row_off[node + 1];
  float di = dinv[node];
  float ax = 0.f;
  for (; e + 8 <= eend; e += 8){
    int s[8]; float w[8]; _Float16 v[8];
    #pragma unroll
    for (int i = 0; i < 8; i++) s[i] = csr_src[e + i];
    #pragma unroll
    for (int i = 0; i < 8; i++) w[i] = dinv[s[i]];
    #pragma unroll
    for (int i = 0; i < 8; i++) v[i] = h16[(size_t)s[i] * 64 + lane];
    #pragma unroll
    for (int i = 0; i < 8; i++) ax = fmaf(w[i], (float)v[i], ax);
  }
  for (; e < eend; ++e){
    int s = csr_src[e];
    ax = fmaf(dinv[s], (float)h16[(size_t)s * 64 + lane], ax);
  }
  float hv = (float)h16[(size_t)node * 64 + lane];
  float o = fmaxf(fmaf(di, ax, di * di * hv) + bias[lane], 0.f);
  float v = o * Wc[lane];
  #pragma unroll
  for (int off = 32; off > 0; off >>= 1) v += __shfl_down(v, off);
  if (lane == 0) out[node] = v + bc[0];
}

// ---------------- launch ----------------

extern "C" void kernel_launch(void* const* d_in, const int* in_sizes, int n_in,
                              void* d_out, int out_size, void* d_ws, size_t ws_size,
                              hipStream_t stream){
  const float* x  = (const float*)d_in[0];
  const int*   ei = (const int*)d_in[1];
  const float* W1 = (const float*)d_in[2];
  const float* b1 = (const float*)d_in[3];
  const float* W2 = (const float*)d_in[4];
  const float* b2 = (const float*)d_in[5];
  const float* W3 = (const float*)d_in[6];
  const float* b3 = (const float*)d_in[7];
  const float* Wc = (const float*)d_in[8];
  const float* bc = (const float*)d_in[9];
  float* out = (float*)d_out;

  int N = in_sizes[0] / 256;
  int E = in_sizes[1] / 2;
  const int* src = ei;
  const int* dst = ei + E;
  int NBK = (N + (1 << BSH) - 1) >> BSH;

  char* ws = (char*)d_ws;
  size_t off = 0;
  auto alloc = [&](size_t bytes) -> char* {
    char* p = ws + off;
    off += (bytes + 511) & ~(size_t)511;
    return p;
  };
  int*      counts  = (int*)     alloc((size_t)N * 4);
  float*    dinv    = (float*)   alloc((size_t)N * 4);
  int*      row_off = (int*)     alloc(((size_t)N + 1) * 4);
  int*      bsum    = (int*)     alloc(1024);
  int*      bsum_ex = (int*)     alloc(1024);
  int*      bcur    = (int*)     alloc((size_t)NBK * 4);
  unsigned* tmp     = (unsigned*)alloc((size_t)E * 4);
  int*      csr_src = (int*)     alloc((size_t)E * 4);
  _Float16* bufH    = (_Float16*)alloc((size_t)N * 128 * 2);  // gemm outputs
  _Float16* bufG    = (_Float16*)alloc((size_t)N * 128 * 2);  // agg outputs (fp16)
  _Float16* W1t     = (_Float16*)alloc((size_t)256 * 128 * 2);
  _Float16* W2t     = (_Float16*)alloc((size_t)128 * 128 * 2);
  _Float16* W3t     = (_Float16*)alloc((size_t)128 * 64 * 2);

  int NB = (N + 1023) / 1024;

  // K1: wcvt (224 blocks) || degree count
  hipMemsetAsync(counts, 0, (size_t)N * 4, stream);
  wcvt_count_kernel<<<224 + cdiv(E, 1024), 256, 0, stream>>>(W1, W1t, W2, W2t, W3, W3t, dst, counts, E);
  // K2: scan chain (+ dinv, + bcur init fused)
  partial_dinv_kernel<<<NB, 256, 0, stream>>>(counts, bsum, dinv, N);
  scan_partials_kernel<<<1, 1, 0, stream>>>(bsum, bsum_ex, row_off, NB, N);
  scan_chunk_kernel<<<NB, 256, 0, stream>>>(counts, bsum_ex, row_off, bcur, N);
  // K3: CSR via block-histogram bucket scatter + per-bucket LDS sort
  bucket_scatter_kernel<<<cdiv(E, CH), 256, 0, stream>>>(src, dst, bcur, tmp, E, NBK);
  bucket_sort_kernel<<<NBK, 256, 0, stream>>>(tmp, row_off, csr_src, N);
  // layer 1: x[N,256] @ W1 -> bufH (fp16); agg -> bufG (fp16)
  mgemm_kernel<128, true ><<<cdiv(N, 128), 256, 0, stream>>>(x, W1t, bufH, N, 256);
  agg128h_kernel<<<cdiv(N, 4), 256, 0, stream>>>(bufH, row_off, csr_src, dinv, b1, bufG, N);
  // layer 2
  mgemm_kernel<128, false><<<cdiv(N, 128), 256, 0, stream>>>(bufG, W2t, bufH, N, 128);
  agg128h_kernel<<<cdiv(N, 4), 256, 0, stream>>>(bufH, row_off, csr_src, dinv, b2, bufG, N);
  // layer 3 (128 -> 64) + fused classifier
  mgemm_kernel<64, false><<<cdiv(N, 128), 256, 0, stream>>>(bufG, W3t, bufH, N, 128);
  agg64h_cls_kernel<<<cdiv(N, 4), 256, 0, stream>>>(bufH, row_off, csr_src, dinv, b3, Wc, bc, out, N);
}

// Round 9
// 369.712 us; speedup vs baseline: 1.6689x; 1.1165x over previous
//
#include <hip/hip_runtime.h>
#include <cstdint>
#include <cstddef>

typedef __attribute__((ext_vector_type(4))) float f32x4;
typedef __attribute__((ext_vector_type(8))) _Float16 half8v;
typedef __attribute__((ext_vector_type(2))) _Float16 half2v;

static inline int cdiv(int a, int b){ return (a + b - 1) / b; }

#define BSH 9              // bucket shift: 512 nodes per bucket
#define CH 8192            // edges staged per scatter block

// ---------------- fused: weight-convert (blocks 0..223) || degree count (rest) ----------------

__global__ __launch_bounds__(256) void wcvt_count_kernel(const float* __restrict__ W1, _Float16* __restrict__ W1t,
                                                         const float* __restrict__ W2, _Float16* __restrict__ W2t,
                                                         const float* __restrict__ W3, _Float16* __restrict__ W3t,
                                                         const int* __restrict__ dst, int* __restrict__ counts, int E){
  int b = blockIdx.x;
  if (b < 224){
    int i = b * 256 + threadIdx.x;
    if (b < 128){
      int k = i / 128, n = i & 127;
      W1t[(size_t)n * 256 + k] = (_Float16)W1[i];
    } else if (b < 192){
      int j = i - 128 * 256;
      int k = j / 128, n = j & 127;
      W2t[(size_t)n * 128 + k] = (_Float16)W2[j];
    } else {
      int j = i - 192 * 256;
      int k = j / 64, n = j & 63;
      W3t[(size_t)n * 128 + k] = (_Float16)W3[j];
    }
    return;
  }
  int cb = b - 224;
  int base = cb * 1024 + threadIdx.x;
  #pragma unroll
  for (int j = 0; j < 4; j++){
    int i = base + j * 256;
    if (i < E) atomicAdd(&counts[__builtin_nontemporal_load(dst + i)], 1);
  }
}

// ---------------- block partial sums (+ fused dinv) ----------------

__global__ __launch_bounds__(256) void partial_dinv_kernel(const int* __restrict__ counts, int* __restrict__ bsum,
                                                           float* __restrict__ dinv, int n){
  __shared__ int sdata[256];
  int b = blockIdx.x, t = threadIdx.x;
  int base = b * 1024 + t * 4;
  int s = 0;
  #pragma unroll
  for (int i = 0; i < 4; i++){
    if (base + i < n){
      int c = counts[base + i];
      s += c;
      dinv[base + i] = rsqrtf((float)c + 1.0f);
    }
  }
  sdata[t] = s; __syncthreads();
  for (int off = 128; off > 0; off >>= 1){
    if (t < off) sdata[t] += sdata[t + off];
    __syncthreads();
  }
  if (t == 0) bsum[b] = sdata[0];
}

__global__ void scan_partials_kernel(const int* __restrict__ bsum, int* __restrict__ bsum_ex,
                                     int* __restrict__ row_off, int nblocks, int n){
  int run = 0;
  for (int i = 0; i < nblocks; i++){ bsum_ex[i] = run; run += bsum[i]; }
  row_off[n] = run;
}

// scan chunk; also emits bucket cursors bcur[b] = row_off[b<<BSH]

__global__ __launch_bounds__(256) void scan_chunk_kernel(const int* __restrict__ counts, const int* __restrict__ bsum_ex,
                                                         int* __restrict__ row_off, int* __restrict__ bcur, int n){
  __shared__ int sdata[256];
  int b = blockIdx.x, t = threadIdx.x;
  int base = b * 1024 + t * 4;
  int c0 = (base + 0 < n) ? counts[base + 0] : 0;
  int c1 = (base + 1 < n) ? counts[base + 1] : 0;
  int c2 = (base + 2 < n) ? counts[base + 2] : 0;
  int c3 = (base + 3 < n) ? counts[base + 3] : 0;
  int tsum = c0 + c1 + c2 + c3;
  sdata[t] = tsum; __syncthreads();
  for (int off = 1; off < 256; off <<= 1){
    int v = (t >= off) ? sdata[t - off] : 0;
    __syncthreads();
    sdata[t] += v;
    __syncthreads();
  }
  int run = bsum_ex[b] + sdata[t] - tsum;
  if (base < n && (base & ((1 << BSH) - 1)) == 0) bcur[base >> BSH] = run;
  if (base + 0 < n){ row_off[base + 0] = run; run += c0; }
  if (base + 1 < n){ row_off[base + 1] = run; run += c1; }
  if (base + 2 < n){ row_off[base + 2] = run; run += c2; }
  if (base + 3 < n){ row_off[base + 3] = run; run += c3; }
}

// ---------------- CSR pass 2: block-histogram bucket scatter ----------------

__global__ __launch_bounds__(256) void bucket_scatter_kernel(const int* __restrict__ src, const int* __restrict__ dst,
                                                             int* __restrict__ bcur, unsigned* __restrict__ tmp,
                                                             int E, int NBK){
  __shared__ int hist[1024];
  __shared__ int hbase[1024];
  __shared__ unsigned pk[CH];
  __shared__ unsigned short bkt[CH];
  int t = threadIdx.x;
  int e0 = blockIdx.x * CH;
  int e1 = e0 + CH; if (e1 > E) e1 = E;
  int nloc = e1 - e0;
  for (int i = t; i < NBK; i += 256) hist[i] = 0;
  __syncthreads();
  for (int i = t; i < nloc; i += 256){
    int d = __builtin_nontemporal_load(dst + e0 + i);
    int s = __builtin_nontemporal_load(src + e0 + i);
    int b = d >> BSH;
    pk[i]  = ((unsigned)s << BSH) | (unsigned)(d & ((1 << BSH) - 1));
    bkt[i] = (unsigned short)b;
    atomicAdd(&hist[b], 1);
  }
  __syncthreads();
  for (int i = t; i < NBK; i += 256){
    int h = hist[i];
    hbase[i] = h ? atomicAdd(&bcur[i], h) : 0;
    hist[i] = 0;                         // reuse as intra-block cursor
  }
  __syncthreads();
  for (int i = t; i < nloc; i += 256){
    int b = bkt[i];
    int pos = atomicAdd(&hist[b], 1);
    tmp[hbase[b] + pos] = pk[i];
  }
}

// ---------------- CSR pass 3: per-bucket LDS-cursor sort, writes within a 32KB window ----------------

__global__ __launch_bounds__(256) void bucket_sort_kernel(const unsigned* __restrict__ tmp, const int* __restrict__ row_off,
                                                          int* __restrict__ csr_src, int N){
  __shared__ int lcur[1 << BSH];
  int g = blockIdx.x;
  int base = g << BSH;
  int nloc = N - base; if (nloc > (1 << BSH)) nloc = (1 << BSH);
  int t = threadIdx.x;
  for (int i = t; i < nloc; i += 256) lcur[i] = row_off[base + i];
  __syncthreads();
  int rs = row_off[base], re = row_off[base + nloc];
  for (int i = rs + t; i < re; i += 256){
    unsigned v = tmp[i];
    int slot = atomicAdd(&lcur[v & ((1 << BSH) - 1)], 1);
    csr_src[slot] = (int)(v >> BSH);
  }
}

// ---------------- MFMA GEMM: C16[row] = fp16(dscale[row] * (A @ Bt^T)[row]), Bt is [BN x K] fp16 ----------------
// BM=128, BK=32, 4 waves. v_mfma_f32_16x16x32_f16:
//   A: lane l row (l&15), k = 8*(l>>4)+{0..7}; B: lane l col (l&15), same k
//   D: lane l reg r -> row = 4*(l>>4)+r, col = (l&15)
// dscale folds the GCN dinv row-scaling into the epilogue: h' = dinv * (A@W).

template<int BN, bool A32IN>
__global__ __launch_bounds__(256) void mgemm_kernel(const void* __restrict__ Ain, const _Float16* __restrict__ Bt,
                                                    _Float16* __restrict__ C16, const float* __restrict__ dscale,
                                                    int M, int K){
  constexpr int BM = 128, LD = 40;   // stride 40 halves: 16B-aligned rows, <=2-way bank aliasing
  constexpr int MF = (BN == 128) ? 4 : 2;
  __shared__ _Float16 As[BM * LD];
  __shared__ _Float16 Bs[BN * LD];
  const float*    A32 = (const float*)Ain;
  const _Float16* A16 = (const _Float16*)Ain;
  int t = threadIdx.x;
  int w = t >> 6, l = t & 63;
  int m0 = blockIdx.x * BM;
  int wm = (BN == 128) ? (w >> 1) * 64 : w * 32;
  int wn = (BN == 128) ? (w & 1) * 64 : 0;
  int lr = l & 15;
  int kg = (l >> 4) * 8;

  f32x4 acc[MF][4];
  #pragma unroll
  for (int i = 0; i < MF; i++)
    #pragma unroll
    for (int j = 0; j < 4; j++){
      f32x4 z = {0.f, 0.f, 0.f, 0.f};
      acc[i][j] = z;
    }

  for (int k0 = 0; k0 < K; k0 += 32){
    __syncthreads();
    #pragma unroll
    for (int j = 0; j < (BM * 4) / 256; j++){
      int i = t + j * 256;
      int row = i >> 2, c = i & 3;
      int gr = m0 + row;
      half8v hv = {(_Float16)0, (_Float16)0, (_Float16)0, (_Float16)0,
                   (_Float16)0, (_Float16)0, (_Float16)0, (_Float16)0};
      if (gr < M){
        if (A32IN){
          const float* ap = A32 + (size_t)gr * K + k0 + c * 8;
          float4 f0 = *reinterpret_cast<const float4*>(ap);
          float4 f1 = *reinterpret_cast<const float4*>(ap + 4);
          hv[0] = (_Float16)f0.x; hv[1] = (_Float16)f0.y; hv[2] = (_Float16)f0.z; hv[3] = (_Float16)f0.w;
          hv[4] = (_Float16)f1.x; hv[5] = (_Float16)f1.y; hv[6] = (_Float16)f1.z; hv[7] = (_Float16)f1.w;
        } else {
          hv = *reinterpret_cast<const half8v*>(A16 + (size_t)gr * K + k0 + c * 8);
        }
      }
      *reinterpret_cast<half8v*>(&As[row * LD + c * 8]) = hv;
    }
    #pragma unroll
    for (int j = 0; j < (BN * 4) / 256; j++){
      int i = t + j * 256;
      int row = i >> 2, c = i & 3;
      *reinterpret_cast<half8v*>(&Bs[row * LD + c * 8]) =
        *reinterpret_cast<const half8v*>(Bt + (size_t)row * K + k0 + c * 8);
    }
    __syncthreads();
    half8v af[MF];
    #pragma unroll
    for (int mf = 0; mf < MF; mf++)
      af[mf] = *reinterpret_cast<const half8v*>(&As[(wm + mf * 16 + lr) * LD + kg]);
    #pragma unroll
    for (int nf = 0; nf < 4; nf++){
      half8v bf = *reinterpret_cast<const half8v*>(&Bs[(wn + nf * 16 + lr) * LD + kg]);
      #pragma unroll
      for (int mf = 0; mf < MF; mf++)
        acc[mf][nf] = __builtin_amdgcn_mfma_f32_16x16x32_f16(af[mf], bf, acc[mf][nf], 0, 0, 0);
    }
  }
  #pragma unroll
  for (int mf = 0; mf < MF; mf++){
    #pragma unroll
    for (int r = 0; r < 4; r++){
      int row = m0 + wm + mf * 16 + (l >> 4) * 4 + r;
      if (row < M){
        float sc = dscale[row];
        #pragma unroll
        for (int nf = 0; nf < 4; nf++)
          C16[(size_t)row * BN + wn + nf * 16 + lr] = (_Float16)(sc * acc[mf][nf][r]);
      }
    }
  }
}

// ---------------- aggregation: out = relu(di * (sum_{s in N(i)} h'_s + h'_i) + b) ----------------
// h' is already dinv-scaled (GEMM epilogue). Inner loop = pure row-sum.
// Indices: one coalesced load per 64 edges (csr_src[e+lane]) + __shfl broadcast; 16 gathers in flight.

__global__ __launch_bounds__(256) void agg128h_kernel(const _Float16* __restrict__ h16, const int* __restrict__ row_off,
                                                      const int* __restrict__ csr_src, const float* __restrict__ dinv,
                                                      const float* __restrict__ bias, _Float16* __restrict__ out16, int n){
  int node = blockIdx.x * 4 + (threadIdx.x >> 6);
  if (node >= n) return;
  int lane = threadIdx.x & 63;
  int e = row_off[node], eend = row_off[node + 1];
  float di = dinv[node];
  half2v sv = *reinterpret_cast<const half2v*>(h16 + (size_t)node * 128 + lane * 2);
  float ax = (float)sv[0], ay = (float)sv[1];
  while (e < eend){
    int m = eend - e; if (m > 64) m = 64;
    int idx = (lane < m) ? csr_src[e + lane] : 0;
    int i = 0;
    for (; i + 16 <= m; i += 16){
      half2v v[16];
      #pragma unroll
      for (int j = 0; j < 16; j++){
        int s = __shfl(idx, i + j);
        v[j] = *reinterpret_cast<const half2v*>(h16 + (size_t)s * 128 + lane * 2);
      }
      #pragma unroll
      for (int j = 0; j < 16; j++){ ax += (float)v[j][0]; ay += (float)v[j][1]; }
    }
    for (; i + 4 <= m; i += 4){
      half2v v[4];
      #pragma unroll
      for (int j = 0; j < 4; j++){
        int s = __shfl(idx, i + j);
        v[j] = *reinterpret_cast<const half2v*>(h16 + (size_t)s * 128 + lane * 2);
      }
      #pragma unroll
      for (int j = 0; j < 4; j++){ ax += (float)v[j][0]; ay += (float)v[j][1]; }
    }
    for (; i < m; i++){
      int s = __shfl(idx, i);
      half2v v = *reinterpret_cast<const half2v*>(h16 + (size_t)s * 128 + lane * 2);
      ax += (float)v[0]; ay += (float)v[1];
    }
    e += m;
  }
  float2 bv = *reinterpret_cast<const float2*>(bias + lane * 2);
  float ox = fmaxf(fmaf(di, ax, bv.x), 0.f);
  float oy = fmaxf(fmaf(di, ay, bv.y), 0.f);
  half2v o; o[0] = (_Float16)ox; o[1] = (_Float16)oy;
  *reinterpret_cast<half2v*>(out16 + (size_t)node * 128 + lane * 2) = o;
}

// layer-3 agg (64-dim, h' pre-scaled) with fused classifier: out[node] = dot(relu(di*rowsum + b), Wc) + bc

__global__ __launch_bounds__(256) void agg64h_cls_kernel(const _Float16* __restrict__ h16, const int* __restrict__ row_off,
                                                         const int* __restrict__ csr_src, const float* __restrict__ dinv,
                                                         const float* __restrict__ bias, const float* __restrict__ Wc,
                                                         const float* __restrict__ bc, float* __restrict__ out, int n){
  int node = blockIdx.x * 4 + (threadIdx.x >> 6);
  if (node >= n) return;
  int lane = threadIdx.x & 63;
  int e = row_off[node], eend = row_off[node + 1];
  float di = dinv[node];
  float a = (float)h16[(size_t)node * 64 + lane];
  while (e < eend){
    int m = eend - e; if (m > 64) m = 64;
    int idx = (lane < m) ? csr_src[e + lane] : 0;
    int i = 0;
    for (; i + 16 <= m; i += 16){
      _Float16 v[16];
      #pragma unroll
      for (int j = 0; j < 16; j++){
        int s = __shfl(idx, i + j);
        v[j] = h16[(size_t)s * 64 + lane];
      }
      #pragma unroll
      for (int j = 0; j < 16; j++) a += (float)v[j];
    }
    for (; i + 4 <= m; i += 4){
      _Float16 v[4];
      #pragma unroll
      for (int j = 0; j < 4; j++){
        int s = __shfl(idx, i + j);
        v[j] = h16[(size_t)s * 64 + lane];
      }
      #pragma unroll
      for (int j = 0; j < 4; j++) a += (float)v[j];
    }
    for (; i < m; i++){
      int s = __shfl(idx, i);
      a += (float)h16[(size_t)s * 64 + lane];
    }
    e += m;
  }
  float o = fmaxf(fmaf(di, a, bias[lane]), 0.f);
  float v = o * Wc[lane];
  #pragma unroll
  for (int off = 32; off > 0; off >>= 1) v += __shfl_down(v, off);
  if (lane == 0) out[node] = v + bc[0];
}

// ---------------- launch ----------------

extern "C" void kernel_launch(void* const* d_in, const int* in_sizes, int n_in,
                              void* d_out, int out_size, void* d_ws, size_t ws_size,
                              hipStream_t stream){
  const float* x  = (const float*)d_in[0];
  const int*   ei = (const int*)d_in[1];
  const float* W1 = (const float*)d_in[2];
  const float* b1 = (const float*)d_in[3];
  const float* W2 = (const float*)d_in[4];
  const float* b2 = (const float*)d_in[5];
  const float* W3 = (const float*)d_in[6];
  const float* b3 = (const float*)d_in[7];
  const float* Wc = (const float*)d_in[8];
  const float* bc = (const float*)d_in[9];
  float* out = (float*)d_out;

  int N = in_sizes[0] / 256;
  int E = in_sizes[1] / 2;
  const int* src = ei;
  const int* dst = ei + E;
  int NBK = (N + (1 << BSH) - 1) >> BSH;

  char* ws = (char*)d_ws;
  size_t off = 0;
  auto alloc = [&](size_t bytes) -> char* {
    char* p = ws + off;
    off += (bytes + 511) & ~(size_t)511;
    return p;
  };
  int*      counts  = (int*)     alloc((size_t)N * 4);
  float*    dinv    = (float*)   alloc((size_t)N * 4);
  int*      row_off = (int*)     alloc(((size_t)N + 1) * 4);
  int*      bsum    = (int*)     alloc(1024);
  int*      bsum_ex = (int*)     alloc(1024);
  int*      bcur    = (int*)     alloc((size_t)NBK * 4);
  unsigned* tmp     = (unsigned*)alloc((size_t)E * 4);
  int*      csr_src = (int*)     alloc((size_t)E * 4);
  _Float16* bufH    = (_Float16*)alloc((size_t)N * 128 * 2);  // gemm outputs (dinv-scaled)
  _Float16* bufG    = (_Float16*)alloc((size_t)N * 128 * 2);  // agg outputs (fp16)
  _Float16* W1t     = (_Float16*)alloc((size_t)256 * 128 * 2);
  _Float16* W2t     = (_Float16*)alloc((size_t)128 * 128 * 2);
  _Float16* W3t     = (_Float16*)alloc((size_t)128 * 64 * 2);

  int NB = (N + 1023) / 1024;

  // K1: wcvt (224 blocks) || degree count
  hipMemsetAsync(counts, 0, (size_t)N * 4, stream);
  wcvt_count_kernel<<<224 + cdiv(E, 1024), 256, 0, stream>>>(W1, W1t, W2, W2t, W3, W3t, dst, counts, E);
  // K2: scan chain (+ dinv, + bcur init fused)
  partial_dinv_kernel<<<NB, 256, 0, stream>>>(counts, bsum, dinv, N);
  scan_partials_kernel<<<1, 1, 0, stream>>>(bsum, bsum_ex, row_off, NB, N);
  scan_chunk_kernel<<<NB, 256, 0, stream>>>(counts, bsum_ex, row_off, bcur, N);
  // K3: CSR via block-histogram bucket scatter + per-bucket LDS sort
  bucket_scatter_kernel<<<cdiv(E, CH), 256, 0, stream>>>(src, dst, bcur, tmp, E, NBK);
  bucket_sort_kernel<<<NBK, 256, 0, stream>>>(tmp, row_off, csr_src, N);
  // layer 1: bufH = dinv*(x@W1) fp16; agg -> bufG
  mgemm_kernel<128, true ><<<cdiv(N, 128), 256, 0, stream>>>(x, W1t, bufH, dinv, N, 256);
  agg128h_kernel<<<cdiv(N, 4), 256, 0, stream>>>(bufH, row_off, csr_src, dinv, b1, bufG, N);
  // layer 2
  mgemm_kernel<128, false><<<cdiv(N, 128), 256, 0, stream>>>(bufG, W2t, bufH, dinv, N, 128);
  agg128h_kernel<<<cdiv(N, 4), 256, 0, stream>>>(bufH, row_off, csr_src, dinv, b2, bufG, N);
  // layer 3 (128 -> 64) + fused classifier
  mgemm_kernel<64, false><<<cdiv(N, 128), 256, 0, stream>>>(bufG, W3t, bufH, dinv, N, 128);
  agg64h_cls_kernel<<<cdiv(N, 4), 256, 0, stream>>>(bufH, row_off, csr_src, dinv, b3, Wc, bc, out, N);
}

// Round 10
// 317.566 us; speedup vs baseline: 1.9430x; 1.1642x over previous
//
#include <hip/hip_runtime.h>
#include <cstdint>
#include <cstddef>

typedef __attribute__((ext_vector_type(4))) float f32x4;
typedef __attribute__((ext_vector_type(8))) _Float16 half8v;
typedef __attribute__((ext_vector_type(2))) _Float16 half2v;

static inline int cdiv(int a, int b){ return (a + b - 1) / b; }

#define BSH 9              // bucket shift: 512 nodes per bucket
#define CH 8192            // edges per scatter block
#define HCH 8192           // edges per histogram block

// ---------------- K1: weight-convert (blocks 0..223) || bucket histogram (rest) ----------------
// Bucket histogram: LDS counters over NBK buckets, one global atomic per (block,bucket).
// Replaces 1.6M random global atomics (66us) with 1.6M LDS atomics + 38K global (predict ~8us).

__global__ __launch_bounds__(256) void wcvt_bhist_kernel(const float* __restrict__ W1, _Float16* __restrict__ W1t,
                                                         const float* __restrict__ W2, _Float16* __restrict__ W2t,
                                                         const float* __restrict__ W3, _Float16* __restrict__ W3t,
                                                         const int* __restrict__ dst, int* __restrict__ bktcnt,
                                                         int E, int NBK){
  __shared__ int hist[1024];
  int b = blockIdx.x, t = threadIdx.x;
  if (b < 224){
    int i = b * 256 + t;
    if (b < 128){
      int k = i / 128, n = i & 127;
      W1t[(size_t)n * 256 + k] = (_Float16)W1[i];
    } else if (b < 192){
      int j = i - 128 * 256;
      int k = j / 128, n = j & 127;
      W2t[(size_t)n * 128 + k] = (_Float16)W2[j];
    } else {
      int j = i - 192 * 256;
      int k = j / 64, n = j & 63;
      W3t[(size_t)n * 128 + k] = (_Float16)W3[j];
    }
    return;
  }
  int cb = b - 224;
  for (int i = t; i < NBK; i += 256) hist[i] = 0;
  __syncthreads();
  int e0 = cb * HCH;
  int e1 = e0 + HCH; if (e1 > E) e1 = E;
  for (int i = e0 + t; i < e1; i += 256){
    int d = __builtin_nontemporal_load(dst + i);
    atomicAdd(&hist[d >> BSH], 1);
  }
  __syncthreads();
  for (int i = t; i < NBK; i += 256){
    int h = hist[i];
    if (h) atomicAdd(&bktcnt[i], h);
  }
}

// ---------------- K2: one-block scan over NBK bucket counts -> bbase, bcur ----------------

__global__ __launch_bounds__(256) void bucket_scan_kernel(const int* __restrict__ bktcnt, int* __restrict__ bbase,
                                                          int* __restrict__ bcur, int NBK, int E){
  __shared__ int sdata[256];
  int t = threadIdx.x;
  int c = (t < NBK) ? bktcnt[t] : 0;
  sdata[t] = c;
  __syncthreads();
  for (int off = 1; off < 256; off <<= 1){
    int v = (t >= off) ? sdata[t - off] : 0;
    __syncthreads();
    sdata[t] += v;
    __syncthreads();
  }
  if (t < NBK){
    int ex = sdata[t] - c;
    bbase[t] = ex;
    bcur[t] = ex;
  }
  if (t == 0) bbase[NBK] = E;
}

// ---------------- K3: block-histogram bucket scatter (unchanged structure) ----------------

__global__ __launch_bounds__(256) void bucket_scatter_kernel(const int* __restrict__ src, const int* __restrict__ dst,
                                                             int* __restrict__ bcur, unsigned* __restrict__ tmp,
                                                             int E, int NBK){
  __shared__ int hist[1024];
  __shared__ int hbase[1024];
  __shared__ unsigned pk[CH];
  __shared__ unsigned short bkt[CH];
  int t = threadIdx.x;
  int e0 = blockIdx.x * CH;
  int e1 = e0 + CH; if (e1 > E) e1 = E;
  int nloc = e1 - e0;
  for (int i = t; i < NBK; i += 256) hist[i] = 0;
  __syncthreads();
  for (int i = t; i < nloc; i += 256){
    int d = __builtin_nontemporal_load(dst + e0 + i);
    int s = __builtin_nontemporal_load(src + e0 + i);
    int b = d >> BSH;
    pk[i]  = ((unsigned)s << BSH) | (unsigned)(d & ((1 << BSH) - 1));
    bkt[i] = (unsigned short)b;
    atomicAdd(&hist[b], 1);
  }
  __syncthreads();
  for (int i = t; i < NBK; i += 256){
    int h = hist[i];
    hbase[i] = h ? atomicAdd(&bcur[i], h) : 0;
    hist[i] = 0;                         // reuse as intra-block cursor
  }
  __syncthreads();
  for (int i = t; i < nloc; i += 256){
    int b = bkt[i];
    int pos = atomicAdd(&hist[b], 1);
    tmp[hbase[b] + pos] = pk[i];
  }
}

// ---------------- K4: per-bucket build: node histogram -> dinv + row_off (LDS scan) -> cursor sort ----------------

__global__ __launch_bounds__(256) void bucket_build_kernel(const unsigned* __restrict__ tmp, const int* __restrict__ bbase,
                                                           int* __restrict__ row_off, float* __restrict__ dinv,
                                                           int* __restrict__ csr_src, int N, int E, int NBK){
  __shared__ int hist[512];
  __shared__ int sdata[256];
  __shared__ int lofs[512];
  int g = blockIdx.x;
  int base = g << BSH;
  int nloc = N - base; if (nloc > 512) nloc = 512;
  int t = threadIdx.x;
  int rs = bbase[g], re = bbase[g + 1];
  hist[t] = 0; hist[t + 256] = 0;
  __syncthreads();
  for (int i = rs + t; i < re; i += 256)
    atomicAdd(&hist[tmp[i] & 511], 1);
  __syncthreads();
  int h0 = hist[2 * t], h1 = hist[2 * t + 1];
  int pairsum = h0 + h1;
  sdata[t] = pairsum;
  __syncthreads();
  for (int off = 1; off < 256; off <<= 1){
    int v = (t >= off) ? sdata[t - off] : 0;
    __syncthreads();
    sdata[t] += v;
    __syncthreads();
  }
  int ex = sdata[t] - pairsum;
  lofs[2 * t] = ex;
  lofs[2 * t + 1] = ex + h0;
  __syncthreads();
  for (int j = t; j < nloc; j += 256){
    dinv[base + j] = rsqrtf((float)hist[j] + 1.0f);
    row_off[base + j] = rs + lofs[j];
  }
  if (g == NBK - 1 && t == 0) row_off[N] = E;
  __syncthreads();
  for (int j = t; j < 512; j += 256) hist[j] = rs + lofs[j];   // reuse as cursors
  __syncthreads();
  for (int i = rs + t; i < re; i += 256){
    unsigned v = tmp[i];
    int slot = atomicAdd(&hist[v & 511], 1);
    csr_src[slot] = (int)(v >> BSH);
  }
}

// ---------------- MFMA GEMM: C16[row] = fp16(dscale[row] * (A @ Bt^T)[row]), Bt is [BN x K] fp16 ----------------
// BM=128, BK=32, 4 waves. v_mfma_f32_16x16x32_f16:
//   A: lane l row (l&15), k = 8*(l>>4)+{0..7}; B: lane l col (l&15), same k
//   D: lane l reg r -> row = 4*(l>>4)+r, col = (l&15)

template<int BN, bool A32IN>
__global__ __launch_bounds__(256) void mgemm_kernel(const void* __restrict__ Ain, const _Float16* __restrict__ Bt,
                                                    _Float16* __restrict__ C16, const float* __restrict__ dscale,
                                                    int M, int K){
  constexpr int BM = 128, LD = 40;   // stride 40 halves: 16B-aligned rows, <=2-way bank aliasing
  constexpr int MF = (BN == 128) ? 4 : 2;
  __shared__ _Float16 As[BM * LD];
  __shared__ _Float16 Bs[BN * LD];
  const float*    A32 = (const float*)Ain;
  const _Float16* A16 = (const _Float16*)Ain;
  int t = threadIdx.x;
  int w = t >> 6, l = t & 63;
  int m0 = blockIdx.x * BM;
  int wm = (BN == 128) ? (w >> 1) * 64 : w * 32;
  int wn = (BN == 128) ? (w & 1) * 64 : 0;
  int lr = l & 15;
  int kg = (l >> 4) * 8;

  f32x4 acc[MF][4];
  #pragma unroll
  for (int i = 0; i < MF; i++)
    #pragma unroll
    for (int j = 0; j < 4; j++){
      f32x4 z = {0.f, 0.f, 0.f, 0.f};
      acc[i][j] = z;
    }

  for (int k0 = 0; k0 < K; k0 += 32){
    __syncthreads();
    #pragma unroll
    for (int j = 0; j < (BM * 4) / 256; j++){
      int i = t + j * 256;
      int row = i >> 2, c = i & 3;
      int gr = m0 + row;
      half8v hv = {(_Float16)0, (_Float16)0, (_Float16)0, (_Float16)0,
                   (_Float16)0, (_Float16)0, (_Float16)0, (_Float16)0};
      if (gr < M){
        if (A32IN){
          const float* ap = A32 + (size_t)gr * K + k0 + c * 8;
          float4 f0 = *reinterpret_cast<const float4*>(ap);
          float4 f1 = *reinterpret_cast<const float4*>(ap + 4);
          hv[0] = (_Float16)f0.x; hv[1] = (_Float16)f0.y; hv[2] = (_Float16)f0.z; hv[3] = (_Float16)f0.w;
          hv[4] = (_Float16)f1.x; hv[5] = (_Float16)f1.y; hv[6] = (_Float16)f1.z; hv[7] = (_Float16)f1.w;
        } else {
          hv = *reinterpret_cast<const half8v*>(A16 + (size_t)gr * K + k0 + c * 8);
        }
      }
      *reinterpret_cast<half8v*>(&As[row * LD + c * 8]) = hv;
    }
    #pragma unroll
    for (int j = 0; j < (BN * 4) / 256; j++){
      int i = t + j * 256;
      int row = i >> 2, c = i & 3;
      *reinterpret_cast<half8v*>(&Bs[row * LD + c * 8]) =
        *reinterpret_cast<const half8v*>(Bt + (size_t)row * K + k0 + c * 8);
    }
    __syncthreads();
    half8v af[MF];
    #pragma unroll
    for (int mf = 0; mf < MF; mf++)
      af[mf] = *reinterpret_cast<const half8v*>(&As[(wm + mf * 16 + lr) * LD + kg]);
    #pragma unroll
    for (int nf = 0; nf < 4; nf++){
      half8v bf = *reinterpret_cast<const half8v*>(&Bs[(wn + nf * 16 + lr) * LD + kg]);
      #pragma unroll
      for (int mf = 0; mf < MF; mf++)
        acc[mf][nf] = __builtin_amdgcn_mfma_f32_16x16x32_f16(af[mf], bf, acc[mf][nf], 0, 0, 0);
    }
  }
  #pragma unroll
  for (int mf = 0; mf < MF; mf++){
    #pragma unroll
    for (int r = 0; r < 4; r++){
      int row = m0 + wm + mf * 16 + (l >> 4) * 4 + r;
      if (row < M){
        float sc = dscale[row];
        #pragma unroll
        for (int nf = 0; nf < 4; nf++)
          C16[(size_t)row * BN + wn + nf * 16 + lr] = (_Float16)(sc * acc[mf][nf][r]);
      }
    }
  }
}

// ---------------- aggregation: out = relu(di * (sum_{s in N(i)} h'_s + h'_i) + b) ----------------
// h' is already dinv-scaled (GEMM epilogue). Inner loop = pure row-sum.
// Indices: one coalesced load per 64 edges (csr_src[e+lane]) + __shfl broadcast; 16 gathers in flight.

__global__ __launch_bounds__(256) void agg128h_kernel(const _Float16* __restrict__ h16, const int* __restrict__ row_off,
                                                      const int* __restrict__ csr_src, const float* __restrict__ dinv,
                                                      const float* __restrict__ bias, _Float16* __restrict__ out16, int n){
  int node = blockIdx.x * 4 + (threadIdx.x >> 6);
  if (node >= n) return;
  int lane = threadIdx.x & 63;
  int e = row_off[node], eend = row_off[node + 1];
  float di = dinv[node];
  half2v sv = *reinterpret_cast<const half2v*>(h16 + (size_t)node * 128 + lane * 2);
  float ax = (float)sv[0], ay = (float)sv[1];
  while (e < eend){
    int m = eend - e; if (m > 64) m = 64;
    int idx = (lane < m) ? csr_src[e + lane] : 0;
    int i = 0;
    for (; i + 16 <= m; i += 16){
      half2v v[16];
      #pragma unroll
      for (int j = 0; j < 16; j++){
        int s = __shfl(idx, i + j);
        v[j] = *reinterpret_cast<const half2v*>(h16 + (size_t)s * 128 + lane * 2);
      }
      #pragma unroll
      for (int j = 0; j < 16; j++){ ax += (float)v[j][0]; ay += (float)v[j][1]; }
    }
    for (; i + 4 <= m; i += 4){
      half2v v[4];
      #pragma unroll
      for (int j = 0; j < 4; j++){
        int s = __shfl(idx, i + j);
        v[j] = *reinterpret_cast<const half2v*>(h16 + (size_t)s * 128 + lane * 2);
      }
      #pragma unroll
      for (int j = 0; j < 4; j++){ ax += (float)v[j][0]; ay += (float)v[j][1]; }
    }
    for (; i < m; i++){
      int s = __shfl(idx, i);
      half2v v = *reinterpret_cast<const half2v*>(h16 + (size_t)s * 128 + lane * 2);
      ax += (float)v[0]; ay += (float)v[1];
    }
    e += m;
  }
  float2 bv = *reinterpret_cast<const float2*>(bias + lane * 2);
  float ox = fmaxf(fmaf(di, ax, bv.x), 0.f);
  float oy = fmaxf(fmaf(di, ay, bv.y), 0.f);
  half2v o; o[0] = (_Float16)ox; o[1] = (_Float16)oy;
  *reinterpret_cast<half2v*>(out16 + (size_t)node * 128 + lane * 2) = o;
}

// layer-3 agg (64-dim, h' pre-scaled) with fused classifier: out[node] = dot(relu(di*rowsum + b), Wc) + bc

__global__ __launch_bounds__(256) void agg64h_cls_kernel(const _Float16* __restrict__ h16, const int* __restrict__ row_off,
                                                         const int* __restrict__ csr_src, const float* __restrict__ dinv,
                                                         const float* __restrict__ bias, const float* __restrict__ Wc,
                                                         const float* __restrict__ bc, float* __restrict__ out, int n){
  int node = blockIdx.x * 4 + (threadIdx.x >> 6);
  if (node >= n) return;
  int lane = threadIdx.x & 63;
  int e = row_off[node], eend = row_off[node + 1];
  float di = dinv[node];
  float a = (float)h16[(size_t)node * 64 + lane];
  while (e < eend){
    int m = eend - e; if (m > 64) m = 64;
    int idx = (lane < m) ? csr_src[e + lane] : 0;
    int i = 0;
    for (; i + 16 <= m; i += 16){
      _Float16 v[16];
      #pragma unroll
      for (int j = 0; j < 16; j++){
        int s = __shfl(idx, i + j);
        v[j] = h16[(size_t)s * 64 + lane];
      }
      #pragma unroll
      for (int j = 0; j < 16; j++) a += (float)v[j];
    }
    for (; i + 4 <= m; i += 4){
      _Float16 v[4];
      #pragma unroll
      for (int j = 0; j < 4; j++){
        int s = __shfl(idx, i + j);
        v[j] = h16[(size_t)s * 64 + lane];
      }
      #pragma unroll
      for (int j = 0; j < 4; j++) a += (float)v[j];
    }
    for (; i < m; i++){
      int s = __shfl(idx, i);
      a += (float)h16[(size_t)s * 64 + lane];
    }
    e += m;
  }
  float o = fmaxf(fmaf(di, a, bias[lane]), 0.f);
  float v = o * Wc[lane];
  #pragma unroll
  for (int off = 32; off > 0; off >>= 1) v += __shfl_down(v, off);
  if (lane == 0) out[node] = v + bc[0];
}

// ---------------- launch ----------------

extern "C" void kernel_launch(void* const* d_in, const int* in_sizes, int n_in,
                              void* d_out, int out_size, void* d_ws, size_t ws_size,
                              hipStream_t stream){
  const float* x  = (const float*)d_in[0];
  const int*   ei = (const int*)d_in[1];
  const float* W1 = (const float*)d_in[2];
  const float* b1 = (const float*)d_in[3];
  const float* W2 = (const float*)d_in[4];
  const float* b2 = (const float*)d_in[5];
  const float* W3 = (const float*)d_in[6];
  const float* b3 = (const float*)d_in[7];
  const float* Wc = (const float*)d_in[8];
  const float* bc = (const float*)d_in[9];
  float* out = (float*)d_out;

  int N = in_sizes[0] / 256;
  int E = in_sizes[1] / 2;
  const int* src = ei;
  const int* dst = ei + E;
  int NBK = (N + (1 << BSH) - 1) >> BSH;   // 196 for N=100000

  char* ws = (char*)d_ws;
  size_t off = 0;
  auto alloc = [&](size_t bytes) -> char* {
    char* p = ws + off;
    off += (bytes + 511) & ~(size_t)511;
    return p;
  };
  int*      bktcnt  = (int*)     alloc((size_t)NBK * 4);
  int*      bbase   = (int*)     alloc(((size_t)NBK + 1) * 4);
  int*      bcur    = (int*)     alloc((size_t)NBK * 4);
  float*    dinv    = (float*)   alloc((size_t)N * 4);
  int*      row_off = (int*)     alloc(((size_t)N + 1) * 4);
  unsigned* tmp     = (unsigned*)alloc((size_t)E * 4);
  int*      csr_src = (int*)     alloc((size_t)E * 4);
  _Float16* bufH    = (_Float16*)alloc((size_t)N * 128 * 2);  // gemm outputs (dinv-scaled)
  _Float16* bufG    = (_Float16*)alloc((size_t)N * 128 * 2);  // agg outputs (fp16)
  _Float16* W1t     = (_Float16*)alloc((size_t)256 * 128 * 2);
  _Float16* W2t     = (_Float16*)alloc((size_t)128 * 128 * 2);
  _Float16* W3t     = (_Float16*)alloc((size_t)128 * 64 * 2);

  // K1: wcvt || bucket histogram
  hipMemsetAsync(bktcnt, 0, (size_t)NBK * 4, stream);
  wcvt_bhist_kernel<<<224 + cdiv(E, HCH), 256, 0, stream>>>(W1, W1t, W2, W2t, W3, W3t, dst, bktcnt, E, NBK);
  // K2: bucket scan
  bucket_scan_kernel<<<1, 256, 0, stream>>>(bktcnt, bbase, bcur, NBK, E);
  // K3: bucket scatter
  bucket_scatter_kernel<<<cdiv(E, CH), 256, 0, stream>>>(src, dst, bcur, tmp, E, NBK);
  // K4: per-bucket build (row_off + dinv + csr_src)
  bucket_build_kernel<<<NBK, 256, 0, stream>>>(tmp, bbase, row_off, dinv, csr_src, N, E, NBK);
  // layer 1: bufH = dinv*(x@W1) fp16; agg -> bufG
  mgemm_kernel<128, true ><<<cdiv(N, 128), 256, 0, stream>>>(x, W1t, bufH, dinv, N, 256);
  agg128h_kernel<<<cdiv(N, 4), 256, 0, stream>>>(bufH, row_off, csr_src, dinv, b1, bufG, N);
  // layer 2
  mgemm_kernel<128, false><<<cdiv(N, 128), 256, 0, stream>>>(bufG, W2t, bufH, dinv, N, 128);
  agg128h_kernel<<<cdiv(N, 4), 256, 0, stream>>>(bufH, row_off, csr_src, dinv, b2, bufG, N);
  // layer 3 (128 -> 64) + fused classifier
  mgemm_kernel<64, false><<<cdiv(N, 128), 256, 0, stream>>>(bufG, W3t, bufH, dinv, N, 128);
  agg64h_cls_kernel<<<cdiv(N, 4), 256, 0, stream>>>(bufH, row_off, csr_src, dinv, b3, Wc, bc, out, N);
}

// Round 11
// 304.605 us; speedup vs baseline: 2.0256x; 1.0426x over previous
//
#include <hip/hip_runtime.h>
#include <cstdint>
#include <cstddef>

typedef __attribute__((ext_vector_type(4))) float f32x4;
typedef __attribute__((ext_vector_type(8))) _Float16 half8v;
typedef __attribute__((ext_vector_type(2))) _Float16 half2v;

static inline int cdiv(int a, int b){ return (a + b - 1) / b; }

#define BSH 9              // bucket shift: 512 nodes per bucket
#define CH 8192            // edges per scatter block
#define HCH 8192           // edges per histogram block

// ---------------- K1: weight-convert (blocks 0..223) || bucket histogram (rest) ----------------

__global__ __launch_bounds__(256) void wcvt_bhist_kernel(const float* __restrict__ W1, _Float16* __restrict__ W1t,
                                                         const float* __restrict__ W2, _Float16* __restrict__ W2t,
                                                         const float* __restrict__ W3, _Float16* __restrict__ W3t,
                                                         const int* __restrict__ dst, int* __restrict__ bktcnt,
                                                         int E, int NBK){
  __shared__ int hist[1024];
  int b = blockIdx.x, t = threadIdx.x;
  if (b < 224){
    int i = b * 256 + t;
    if (b < 128){
      int k = i / 128, n = i & 127;
      W1t[(size_t)n * 256 + k] = (_Float16)W1[i];
    } else if (b < 192){
      int j = i - 128 * 256;
      int k = j / 128, n = j & 127;
      W2t[(size_t)n * 128 + k] = (_Float16)W2[j];
    } else {
      int j = i - 192 * 256;
      int k = j / 64, n = j & 63;
      W3t[(size_t)n * 128 + k] = (_Float16)W3[j];
    }
    return;
  }
  int cb = b - 224;
  for (int i = t; i < NBK; i += 256) hist[i] = 0;
  __syncthreads();
  int e0 = cb * HCH;
  int e1 = e0 + HCH; if (e1 > E) e1 = E;
  for (int i = e0 + t; i < e1; i += 256){
    int d = __builtin_nontemporal_load(dst + i);
    atomicAdd(&hist[d >> BSH], 1);
  }
  __syncthreads();
  for (int i = t; i < NBK; i += 256){
    int h = hist[i];
    if (h) atomicAdd(&bktcnt[i], h);
  }
}

// ---------------- K2: one-block scan over NBK bucket counts -> bbase, bcur ----------------

__global__ __launch_bounds__(256) void bucket_scan_kernel(const int* __restrict__ bktcnt, int* __restrict__ bbase,
                                                          int* __restrict__ bcur, int NBK, int E){
  __shared__ int sdata[256];
  int t = threadIdx.x;
  int c = (t < NBK) ? bktcnt[t] : 0;
  sdata[t] = c;
  __syncthreads();
  for (int off = 1; off < 256; off <<= 1){
    int v = (t >= off) ? sdata[t - off] : 0;
    __syncthreads();
    sdata[t] += v;
    __syncthreads();
  }
  if (t < NBK){
    int ex = sdata[t] - c;
    bbase[t] = ex;
    bcur[t] = ex;
  }
  if (t == 0) bbase[NBK] = E;
}

// ---------------- K3: block-histogram bucket scatter ----------------

__global__ __launch_bounds__(256) void bucket_scatter_kernel(const int* __restrict__ src, const int* __restrict__ dst,
                                                             int* __restrict__ bcur, unsigned* __restrict__ tmp,
                                                             int E, int NBK){
  __shared__ int hist[1024];
  __shared__ int hbase[1024];
  __shared__ unsigned pk[CH];
  __shared__ unsigned short bkt[CH];
  int t = threadIdx.x;
  int e0 = blockIdx.x * CH;
  int e1 = e0 + CH; if (e1 > E) e1 = E;
  int nloc = e1 - e0;
  for (int i = t; i < NBK; i += 256) hist[i] = 0;
  __syncthreads();
  for (int i = t; i < nloc; i += 256){
    int d = __builtin_nontemporal_load(dst + e0 + i);
    int s = __builtin_nontemporal_load(src + e0 + i);
    int b = d >> BSH;
    pk[i]  = ((unsigned)s << BSH) | (unsigned)(d & ((1 << BSH) - 1));
    bkt[i] = (unsigned short)b;
    atomicAdd(&hist[b], 1);
  }
  __syncthreads();
  for (int i = t; i < NBK; i += 256){
    int h = hist[i];
    hbase[i] = h ? atomicAdd(&bcur[i], h) : 0;
    hist[i] = 0;                         // reuse as intra-block cursor
  }
  __syncthreads();
  for (int i = t; i < nloc; i += 256){
    int b = bkt[i];
    int pos = atomicAdd(&hist[b], 1);
    tmp[hbase[b] + pos] = pk[i];
  }
}

// ---------------- K4: per-bucket build: node histogram -> dinv + row_off (LDS scan) -> cursor sort ----------------

__global__ __launch_bounds__(256) void bucket_build_kernel(const unsigned* __restrict__ tmp, const int* __restrict__ bbase,
                                                           int* __restrict__ row_off, float* __restrict__ dinv,
                                                           int* __restrict__ csr_src, int N, int E, int NBK){
  __shared__ int hist[512];
  __shared__ int sdata[256];
  __shared__ int lofs[512];
  int g = blockIdx.x;
  int base = g << BSH;
  int nloc = N - base; if (nloc > 512) nloc = 512;
  int t = threadIdx.x;
  int rs = bbase[g], re = bbase[g + 1];
  hist[t] = 0; hist[t + 256] = 0;
  __syncthreads();
  for (int i = rs + t; i < re; i += 256)
    atomicAdd(&hist[tmp[i] & 511], 1);
  __syncthreads();
  int h0 = hist[2 * t], h1 = hist[2 * t + 1];
  int pairsum = h0 + h1;
  sdata[t] = pairsum;
  __syncthreads();
  for (int off = 1; off < 256; off <<= 1){
    int v = (t >= off) ? sdata[t - off] : 0;
    __syncthreads();
    sdata[t] += v;
    __syncthreads();
  }
  int ex = sdata[t] - pairsum;
  lofs[2 * t] = ex;
  lofs[2 * t + 1] = ex + h0;
  __syncthreads();
  for (int j = t; j < nloc; j += 256){
    dinv[base + j] = rsqrtf((float)hist[j] + 1.0f);
    row_off[base + j] = rs + lofs[j];
  }
  if (g == NBK - 1 && t == 0) row_off[N] = E;
  __syncthreads();
  for (int j = t; j < 512; j += 256) hist[j] = rs + lofs[j];   // reuse as cursors
  __syncthreads();
  for (int i = rs + t; i < re; i += 256){
    unsigned v = tmp[i];
    int slot = atomicAdd(&hist[v & 511], 1);
    csr_src[slot] = (int)(v >> BSH);
  }
}

// ---------------- pipelined MFMA GEMM: C16[row] = fp16(dscale[row] * (A @ Bt^T)[row]) ----------------
// BM=128, BK=32, 4 waves, 2-stage register prefetch: tile k+1's global loads issue before
// tile k's MFMAs -> HBM latency hides under compute (fix for 3.5% MfmaUtil / 20% occ stall).
//   A: lane l row (l&15), k = 8*(l>>4)+{0..7}; B: lane l col (l&15), same k
//   D: lane l reg r -> row = 4*(l>>4)+r, col = (l&15)

template<int BN, bool A32IN>
__global__ __launch_bounds__(256) void mgemm_kernel(const void* __restrict__ Ain, const _Float16* __restrict__ Bt,
                                                    _Float16* __restrict__ C16, const float* __restrict__ dscale,
                                                    int M, int K){
  constexpr int BM = 128, LD = 40;   // stride 40 halves: 16B-aligned rows, <=2-way bank aliasing
  constexpr int MF = (BN == 128) ? 4 : 2;
  constexpr int NBC = (BN * 4) / 256;   // B chunks per thread
  __shared__ _Float16 As[BM * LD];
  __shared__ _Float16 Bs[BN * LD];
  const float*    A32 = (const float*)Ain;
  const _Float16* A16 = (const _Float16*)Ain;
  int t = threadIdx.x;
  int w = t >> 6, l = t & 63;
  int m0 = blockIdx.x * BM;
  int wm = (BN == 128) ? (w >> 1) * 64 : w * 32;
  int wn = (BN == 128) ? (w & 1) * 64 : 0;
  int lr = l & 15;
  int kg = (l >> 4) * 8;

  int arow = t >> 2, ac = t & 3;         // A chunk 0: row 0..63; chunk 1: +64
  int ag0 = m0 + arow, ag1 = m0 + arow + 64;

  f32x4 acc[MF][4];
  #pragma unroll
  for (int i = 0; i < MF; i++)
    #pragma unroll
    for (int j = 0; j < 4; j++){
      f32x4 z = {0.f, 0.f, 0.f, 0.f};
      acc[i][j] = z;
    }

  // prefetch registers
  float4 ar0[2][2];       // A32 path: [chunk][lo/hi float4]
  half8v ar16[2];         // A16 path
  half8v br[NBC];

  auto loadA = [&](int k0){
    if (A32IN){
      #pragma unroll
      for (int j = 0; j < 2; j++){
        int gr = (j == 0) ? ag0 : ag1;
        if (gr < M){
          const float* ap = A32 + (size_t)gr * K + k0 + ac * 8;
          ar0[j][0] = *reinterpret_cast<const float4*>(ap);
          ar0[j][1] = *reinterpret_cast<const float4*>(ap + 4);
        } else {
          ar0[j][0] = make_float4(0.f, 0.f, 0.f, 0.f);
          ar0[j][1] = make_float4(0.f, 0.f, 0.f, 0.f);
        }
      }
    } else {
      #pragma unroll
      for (int j = 0; j < 2; j++){
        int gr = (j == 0) ? ag0 : ag1;
        if (gr < M){
          ar16[j] = *reinterpret_cast<const half8v*>(A16 + (size_t)gr * K + k0 + ac * 8);
        } else {
          half8v z = {(_Float16)0, (_Float16)0, (_Float16)0, (_Float16)0,
                      (_Float16)0, (_Float16)0, (_Float16)0, (_Float16)0};
          ar16[j] = z;
        }
      }
    }
  };
  auto loadB = [&](int k0){
    #pragma unroll
    for (int j = 0; j < NBC; j++){
      int i = t + j * 256;
      int row = i >> 2, c = i & 3;
      br[j] = *reinterpret_cast<const half8v*>(Bt + (size_t)row * K + k0 + c * 8);
    }
  };
  auto storeLDS = [&](){
    #pragma unroll
    for (int j = 0; j < 2; j++){
      int row = arow + j * 64;
      half8v hv;
      if (A32IN){
        hv[0] = (_Float16)ar0[j][0].x; hv[1] = (_Float16)ar0[j][0].y;
        hv[2] = (_Float16)ar0[j][0].z; hv[3] = (_Float16)ar0[j][0].w;
        hv[4] = (_Float16)ar0[j][1].x; hv[5] = (_Float16)ar0[j][1].y;
        hv[6] = (_Float16)ar0[j][1].z; hv[7] = (_Float16)ar0[j][1].w;
      } else {
        hv = ar16[j];
      }
      *reinterpret_cast<half8v*>(&As[row * LD + ac * 8]) = hv;
    }
    #pragma unroll
    for (int j = 0; j < NBC; j++){
      int i = t + j * 256;
      int row = i >> 2, c = i & 3;
      *reinterpret_cast<half8v*>(&Bs[row * LD + c * 8]) = br[j];
    }
  };

  loadA(0); loadB(0);
  for (int k0 = 0; k0 < K; k0 += 32){
    storeLDS();                         // implicit vmcnt wait on staged loads
    __syncthreads();
    if (k0 + 32 < K){ loadA(k0 + 32); loadB(k0 + 32); }   // issue next tile early
    half8v af[MF];
    #pragma unroll
    for (int mf = 0; mf < MF; mf++)
      af[mf] = *reinterpret_cast<const half8v*>(&As[(wm + mf * 16 + lr) * LD + kg]);
    #pragma unroll
    for (int nf = 0; nf < 4; nf++){
      half8v bf = *reinterpret_cast<const half8v*>(&Bs[(wn + nf * 16 + lr) * LD + kg]);
      #pragma unroll
      for (int mf = 0; mf < MF; mf++)
        acc[mf][nf] = __builtin_amdgcn_mfma_f32_16x16x32_f16(af[mf], bf, acc[mf][nf], 0, 0, 0);
    }
    __syncthreads();                    // LDS consumed; next storeLDS may overwrite
  }
  #pragma unroll
  for (int mf = 0; mf < MF; mf++){
    #pragma unroll
    for (int r = 0; r < 4; r++){
      int row = m0 + wm + mf * 16 + (l >> 4) * 4 + r;
      if (row < M){
        float sc = dscale[row];
        #pragma unroll
        for (int nf = 0; nf < 4; nf++)
          C16[(size_t)row * BN + wn + nf * 16 + lr] = (_Float16)(sc * acc[mf][nf][r]);
      }
    }
  }
}

// ---------------- aggregation: out = relu(di * (sum_{s in N(i)} h'_s + h'_i) + b) ----------------

__global__ __launch_bounds__(256) void agg128h_kernel(const _Float16* __restrict__ h16, const int* __restrict__ row_off,
                                                      const int* __restrict__ csr_src, const float* __restrict__ dinv,
                                                      const float* __restrict__ bias, _Float16* __restrict__ out16, int n){
  int node = blockIdx.x * 4 + (threadIdx.x >> 6);
  if (node >= n) return;
  int lane = threadIdx.x & 63;
  int e = row_off[node], eend = row_off[node + 1];
  float di = dinv[node];
  half2v sv = *reinterpret_cast<const half2v*>(h16 + (size_t)node * 128 + lane * 2);
  float ax = (float)sv[0], ay = (float)sv[1];
  while (e < eend){
    int m = eend - e; if (m > 64) m = 64;
    int idx = (lane < m) ? csr_src[e + lane] : 0;
    int i = 0;
    for (; i + 16 <= m; i += 16){
      half2v v[16];
      #pragma unroll
      for (int j = 0; j < 16; j++){
        int s = __shfl(idx, i + j);
        v[j] = *reinterpret_cast<const half2v*>(h16 + (size_t)s * 128 + lane * 2);
      }
      #pragma unroll
      for (int j = 0; j < 16; j++){ ax += (float)v[j][0]; ay += (float)v[j][1]; }
    }
    for (; i + 4 <= m; i += 4){
      half2v v[4];
      #pragma unroll
      for (int j = 0; j < 4; j++){
        int s = __shfl(idx, i + j);
        v[j] = *reinterpret_cast<const half2v*>(h16 + (size_t)s * 128 + lane * 2);
      }
      #pragma unroll
      for (int j = 0; j < 4; j++){ ax += (float)v[j][0]; ay += (float)v[j][1]; }
    }
    for (; i < m; i++){
      int s = __shfl(idx, i);
      half2v v = *reinterpret_cast<const half2v*>(h16 + (size_t)s * 128 + lane * 2);
      ax += (float)v[0]; ay += (float)v[1];
    }
    e += m;
  }
  float2 bv = *reinterpret_cast<const float2*>(bias + lane * 2);
  float ox = fmaxf(fmaf(di, ax, bv.x), 0.f);
  float oy = fmaxf(fmaf(di, ay, bv.y), 0.f);
  half2v o; o[0] = (_Float16)ox; o[1] = (_Float16)oy;
  *reinterpret_cast<half2v*>(out16 + (size_t)node * 128 + lane * 2) = o;
}

// layer-3 agg (64-dim, h' pre-scaled) with fused classifier

__global__ __launch_bounds__(256) void agg64h_cls_kernel(const _Float16* __restrict__ h16, const int* __restrict__ row_off,
                                                         const int* __restrict__ csr_src, const float* __restrict__ dinv,
                                                         const float* __restrict__ bias, const float* __restrict__ Wc,
                                                         const float* __restrict__ bc, float* __restrict__ out, int n){
  int node = blockIdx.x * 4 + (threadIdx.x >> 6);
  if (node >= n) return;
  int lane = threadIdx.x & 63;
  int e = row_off[node], eend = row_off[node + 1];
  float di = dinv[node];
  float a = (float)h16[(size_t)node * 64 + lane];
  while (e < eend){
    int m = eend - e; if (m > 64) m = 64;
    int idx = (lane < m) ? csr_src[e + lane] : 0;
    int i = 0;
    for (; i + 16 <= m; i += 16){
      _Float16 v[16];
      #pragma unroll
      for (int j = 0; j < 16; j++){
        int s = __shfl(idx, i + j);
        v[j] = h16[(size_t)s * 64 + lane];
      }
      #pragma unroll
      for (int j = 0; j < 16; j++) a += (float)v[j];
    }
    for (; i + 4 <= m; i += 4){
      _Float16 v[4];
      #pragma unroll
      for (int j = 0; j < 4; j++){
        int s = __shfl(idx, i + j);
        v[j] = h16[(size_t)s * 64 + lane];
      }
      #pragma unroll
      for (int j = 0; j < 4; j++) a += (float)v[j];
    }
    for (; i < m; i++){
      int s = __shfl(idx, i);
      a += (float)h16[(size_t)s * 64 + lane];
    }
    e += m;
  }
  float o = fmaxf(fmaf(di, a, bias[lane]), 0.f);
  float v = o * Wc[lane];
  #pragma unroll
  for (int off = 32; off > 0; off >>= 1) v += __shfl_down(v, off);
  if (lane == 0) out[node] = v + bc[0];
}

// ---------------- launch ----------------

extern "C" void kernel_launch(void* const* d_in, const int* in_sizes, int n_in,
                              void* d_out, int out_size, void* d_ws, size_t ws_size,
                              hipStream_t stream){
  const float* x  = (const float*)d_in[0];
  const int*   ei = (const int*)d_in[1];
  const float* W1 = (const float*)d_in[2];
  const float* b1 = (const float*)d_in[3];
  const float* W2 = (const float*)d_in[4];
  const float* b2 = (const float*)d_in[5];
  const float* W3 = (const float*)d_in[6];
  const float* b3 = (const float*)d_in[7];
  const float* Wc = (const float*)d_in[8];
  const float* bc = (const float*)d_in[9];
  float* out = (float*)d_out;

  int N = in_sizes[0] / 256;
  int E = in_sizes[1] / 2;
  const int* src = ei;
  const int* dst = ei + E;
  int NBK = (N + (1 << BSH) - 1) >> BSH;   // 196 for N=100000

  char* ws = (char*)d_ws;
  size_t off = 0;
  auto alloc = [&](size_t bytes) -> char* {
    char* p = ws + off;
    off += (bytes + 511) & ~(size_t)511;
    return p;
  };
  int*      bktcnt  = (int*)     alloc((size_t)NBK * 4);
  int*      bbase   = (int*)     alloc(((size_t)NBK + 1) * 4);
  int*      bcur    = (int*)     alloc((size_t)NBK * 4);
  float*    dinv    = (float*)   alloc((size_t)N * 4);
  int*      row_off = (int*)     alloc(((size_t)N + 1) * 4);
  unsigned* tmp     = (unsigned*)alloc((size_t)E * 4);
  int*      csr_src = (int*)     alloc((size_t)E * 4);
  _Float16* bufH    = (_Float16*)alloc((size_t)N * 128 * 2);  // gemm outputs (dinv-scaled)
  _Float16* bufG    = (_Float16*)alloc((size_t)N * 128 * 2);  // agg outputs (fp16)
  _Float16* W1t     = (_Float16*)alloc((size_t)256 * 128 * 2);
  _Float16* W2t     = (_Float16*)alloc((size_t)128 * 128 * 2);
  _Float16* W3t     = (_Float16*)alloc((size_t)128 * 64 * 2);

  // K1: wcvt || bucket histogram
  hipMemsetAsync(bktcnt, 0, (size_t)NBK * 4, stream);
  wcvt_bhist_kernel<<<224 + cdiv(E, HCH), 256, 0, stream>>>(W1, W1t, W2, W2t, W3, W3t, dst, bktcnt, E, NBK);
  // K2: bucket scan
  bucket_scan_kernel<<<1, 256, 0, stream>>>(bktcnt, bbase, bcur, NBK, E);
  // K3: bucket scatter
  bucket_scatter_kernel<<<cdiv(E, CH), 256, 0, stream>>>(src, dst, bcur, tmp, E, NBK);
  // K4: per-bucket build (row_off + dinv + csr_src)
  bucket_build_kernel<<<NBK, 256, 0, stream>>>(tmp, bbase, row_off, dinv, csr_src, N, E, NBK);
  // layer 1: bufH = dinv*(x@W1) fp16; agg -> bufG
  mgemm_kernel<128, true ><<<cdiv(N, 128), 256, 0, stream>>>(x, W1t, bufH, dinv, N, 256);
  agg128h_kernel<<<cdiv(N, 4), 256, 0, stream>>>(bufH, row_off, csr_src, dinv, b1, bufG, N);
  // layer 2
  mgemm_kernel<128, false><<<cdiv(N, 128), 256, 0, stream>>>(bufG, W2t, bufH, dinv, N, 128);
  agg128h_kernel<<<cdiv(N, 4), 256, 0, stream>>>(bufH, row_off, csr_src, dinv, b2, bufG, N);
  // layer 3 (128 -> 64) + fused classifier
  mgemm_kernel<64, false><<<cdiv(N, 128), 256, 0, stream>>>(bufG, W3t, bufH, dinv, N, 128);
  agg64h_cls_kernel<<<cdiv(N, 4), 256, 0, stream>>>(bufH, row_off, csr_src, dinv, b3, Wc, bc, out, N);
}